// Round 9
// baseline (837.361 us; speedup 1.0000x reference)
//
#include <hip/hip_runtime.h>

// HGNN layer, v9 — fp32. v8 pipeline; kNN rebuilt: tiled distance phase
// (LDS 37.9KB -> 10.3KB, occupancy 4 -> 8 blocks/CU) + DPP wave reduction
// (6 VALU stages instead of 12 ds_bpermute) for per-extraction argmin.

#define HB    4
#define HN    2304
#define HC    64
#define HK    11             // K_NEIGS + 1
#define HL    48
#define HW    22             // windows per dim
#define HE2   484            // 22*22 local edges
#define HE    (HN + HE2)
#define HRPB  4              // rows per block == waves per block
#define HTS   576            // m-tile size (4 tiles)
#define NSLOT 36             // keys per lane (2304/64)
#define NPAIRS (HB * HK * HN)   // sum of Dv == 11*N per batch, exact

__global__ void hg9_sentinel(float* out, int n) {
    int i = blockIdx.x * 256 + threadIdx.x;
    if (i < n) out[i] = 12345.0f;
}

__global__ void hg9_init(int* Dv, int* indeg, int* paircnt, float* bnsum, float* bnss) {
    int i = blockIdx.x * 256 + threadIdx.x;
    if (i < HB * HN) { Dv[i] = 0; indeg[i] = 0; }
    if (i == 0) *paircnt = 0;
    if (i < HC) { bnsum[i] = 0.f; bnss[i] = 0.f; }
}

// -------- linear h1 = x W^T + b, xsq, f32 transpose -----------------------
__global__ __launch_bounds__(64) void hg9_linear(const float* x, const float* W,
                                                 const float* bias, float* h1,
                                                 float* xsq, float* xT) {
    int row = blockIdx.x;            // 0..B*N-1
    int t = threadIdx.x;
    __shared__ float xr[HC];
    float v = x[row * HC + t];
    xr[t] = v;
    __syncthreads();
    float sq = v * v;
    #pragma unroll
    for (int o = 32; o > 0; o >>= 1) sq += __shfl_xor(sq, o);
    if (t == 0) xsq[row] = sq;
    int b = row / HN, n = row % HN;
    xT[(b * HC + t) * HN + n] = v;
    float acc = bias[t];
    #pragma unroll 8
    for (int c = 0; c < HC; c++) acc += xr[c] * W[t * HC + c];
    h1[row * HC + t] = acc;
}

// -------- DPP u64 min stage: combine with value from lower lanes ----------
// row_shr:N = 0x110+N, row_bcast15 = 0x142, row_bcast31 = 0x143.
#define HG9_DPP_MIN(v, CTRL)                                                        \
    {                                                                               \
        unsigned int lo_ = (unsigned int)(v), hi_ = (unsigned int)((v) >> 32);      \
        unsigned int plo_ = (unsigned int)__builtin_amdgcn_update_dpp(              \
            (int)lo_, (int)lo_, CTRL, 0xF, 0xF, false);                             \
        unsigned int phi_ = (unsigned int)__builtin_amdgcn_update_dpp(              \
            (int)hi_, (int)hi_, CTRL, 0xF, 0xF, false);                             \
        unsigned long long p_ = ((unsigned long long)phi_ << 32) | plo_;            \
        if (p_ < (v)) (v) = p_;                                                     \
    }

// -------- kNN: tiled block distances, register keys, DPP extraction -------
// SEL=0: pick 11 nearest per row (incl self), count Dv[neighbor].
// SEL=1: pick Dv[row] nearest, emit (b,p,m) pairs, count node in-degree.
__device__ __forceinline__ void hg9_knn_body(const float* xT, const float* xsq,
                                             int* Dv, int* indeg,
                                             unsigned int* pairs, int* paircnt,
                                             int SEL) {
    __shared__ float dtile[HRPB][HTS];   // 9 KB
    __shared__ float xr[HRPB][HC];       // 1 KB
    const int t = threadIdx.x;
    const int b = blockIdx.x / (HN / HRPB);
    const int n0 = (blockIdx.x % (HN / HRPB)) * HRPB;
    const int r = t >> 6;
    const int lane = t & 63;
    xr[r][lane] = xT[(b * HC + lane) * HN + n0 + r];
    __syncthreads();
    float xs[HRPB];
    #pragma unroll
    for (int q = 0; q < HRPB; q++) xs[q] = xsq[b * HN + n0 + q];

    unsigned int key[NSLOT];             // orderable-u32 distance keys
    #pragma unroll
    for (int tt = 0; tt < HN / HTS; tt++) {       // 4 tiles
        const int m0 = tt * HTS;
        for (int mi = t; mi < HTS; mi += 256) {   // identical fp order to v8
            int m = m0 + mi;
            float dot0 = 0.f, dot1 = 0.f, dot2 = 0.f, dot3 = 0.f;
            #pragma unroll 8
            for (int c = 0; c < HC; c++) {
                float xv = xT[(b * HC + c) * HN + m];
                dot0 += xr[0][c] * xv;
                dot1 += xr[1][c] * xv;
                dot2 += xr[2][c] * xv;
                dot3 += xr[3][c] * xv;
            }
            float xsm = xsq[b * HN + m];
            dtile[0][mi] = xs[0] + xsm - 2.f * dot0;
            dtile[1][mi] = xs[1] + xsm - 2.f * dot1;
            dtile[2][mi] = xs[2] + xsm - 2.f * dot2;
            dtile[3][mi] = xs[3] + xsm - 2.f * dot3;
        }
        __syncthreads();
        #pragma unroll
        for (int j = 0; j < HTS / 64; j++) {      // fold 9 slots into registers
            float f = dtile[r][lane + 64 * j];
            unsigned int ub = __float_as_uint(f);
            key[tt * (HTS / 64) + j] =
                ub ^ (((unsigned int)(((int)ub) >> 31)) | 0x80000000u);
        }
        __syncthreads();
    }

    // ---- selection: slot s of lane l is node m = l + 64*s. No barriers.
    const int p = n0 + r;
    const int kk = SEL ? max(Dv[b * HN + p], 1) : HK;
    int base = 0;
    if (SEL) {                                   // reserve kk pair slots once
        if (lane == 0) base = atomicAdd(paircnt, kk);
        base = __shfl(base, 0);
    }
    const unsigned long long UMAX = ~0ull;
    unsigned long long last = 0;                 // packed keys are all > 0
    for (int j = 0; j < kk; j++) {
        unsigned long long a0 = UMAX, a1 = UMAX, a2 = UMAX, a3 = UMAX;
        #pragma unroll
        for (int i = 0; i < NSLOT / 4; i++) {    // 4 independent chains
            #pragma unroll
            for (int q = 0; q < 4; q++) {
                int s = 4 * i + q;
                unsigned long long pk =
                    ((unsigned long long)key[s] << 12) | (unsigned)(lane + (s << 6));
                unsigned long long cand = (pk > last) ? pk : UMAX;
                if (q == 0) { if (cand < a0) a0 = cand; }
                else if (q == 1) { if (cand < a1) a1 = cand; }
                else if (q == 2) { if (cand < a2) a2 = cand; }
                else             { if (cand < a3) a3 = cand; }
            }
        }
        unsigned long long m01 = a0 < a1 ? a0 : a1;
        unsigned long long m23 = a2 < a3 ? a2 : a3;
        unsigned long long best = m01 < m23 ? m01 : m23;
        HG9_DPP_MIN(best, 0x111);                // row_shr:1
        HG9_DPP_MIN(best, 0x112);                // row_shr:2
        HG9_DPP_MIN(best, 0x114);                // row_shr:4
        HG9_DPP_MIN(best, 0x118);                // row_shr:8
        HG9_DPP_MIN(best, 0x142);                // row_bcast15
        HG9_DPP_MIN(best, 0x143);                // row_bcast31  -> lane 63
        unsigned int wlo = (unsigned int)__builtin_amdgcn_readlane(
            (int)(unsigned int)best, 63);
        unsigned int whi = (unsigned int)__builtin_amdgcn_readlane(
            (int)(unsigned int)(best >> 32), 63);
        last = ((unsigned long long)whi << 32) | wlo;   // wave-uniform
        if (lane == 0) {
            int bi = (int)(last & 0xFFFu);
            if (SEL) {
                atomicAdd(&indeg[b * HN + bi], 1);
                pairs[base + j] = ((unsigned)b << 24) | ((unsigned)p << 12) | (unsigned)bi;
            } else {
                atomicAdd(&Dv[b * HN + bi], 1);
            }
        }
    }
}

__global__ __launch_bounds__(256) void hg9_knn_count(const float* xT, const float* xsq,
                                                     int* Dv, int* indeg,
                                                     unsigned int* pairs, int* paircnt) {
    hg9_knn_body(xT, xsq, Dv, indeg, pairs, paircnt, 0);
}

__global__ __launch_bounds__(256) void hg9_knn_select(const float* xT, const float* xsq,
                                                      int* Dv, int* indeg,
                                                      unsigned int* pairs, int* paircnt) {
    hg9_knn_body(xT, xsq, Dv, indeg, pairs, paircnt, 1);
}

__device__ __forceinline__ int hg9_lo(int rc) { return max(0, (rc - 3) / 2); }
__device__ __forceinline__ int hg9_hi(int rc) { return min(HW - 1, rc / 2); }

// -------- y = Dv^-1/2 * h1 (in place) -------------------------------------
__global__ __launch_bounds__(256) void hg9_scale(float* h1, const int* indeg) {
    int i = blockIdx.x * 256 + threadIdx.x;
    int node = i >> 6;
    int n = node % HN;
    int r = n / HL, c = n % HL;
    int cover = max(0, hg9_hi(r) - hg9_lo(r) + 1) * max(0, hg9_hi(c) - hg9_lo(c) + 1);
    int dvn = max(indeg[node] + cover, 1);
    h1[i] *= rsqrtf((float)dvn);
}

// -------- zero z (kNN-edge part) and h2, one kernel -----------------------
__global__ void hg9_zero(float* z, float* h2) {
    int i = blockIdx.x * 256 + threadIdx.x;      // over B*N*C
    int b = i / (HN * HC), rem = i % (HN * HC);
    z[b * HE * HC + rem] = 0.f;                  // window part written by edge kernel
    h2[i] = 0.f;
}

// -------- fused edge kernel: kNN scatter + window means -------------------
__global__ __launch_bounds__(256) void hg9_edge(const unsigned int* pairs, const int* Dv,
                                                const float* y, float* z) {
    int wv = (blockIdx.x * 256 + threadIdx.x) >> 6;
    int lane = threadIdx.x & 63;
    if (wv < NPAIRS) {
        unsigned int pk = pairs[wv];
        int b = pk >> 24;
        if (b >= HB) return;                     // defensive (poison)
        int p = (pk >> 12) & 0xFFF, m = pk & 0xFFF;
        float invde = 1.f / (float)max(Dv[b * HN + p], 1);
        atomicAdd(&z[(b * HE + p) * HC + lane], y[(b * HN + m) * HC + lane] * invde);
    } else {
        int w2 = wv - NPAIRS;
        if (w2 >= HB * HE2) return;
        int b = w2 / HE2, w = w2 % HE2;
        int wr = w / HW, wc = w % HW;
        float acc = 0.f;
        #pragma unroll
        for (int i = 0; i < 5; i++)
            #pragma unroll
            for (int j = 0; j < 5; j++)
                acc += y[(b * HN + (wr * 2 + i) * HL + wc * 2 + j) * HC + lane];
        z[(b * HE + HN + w) * HC + lane] = acc * (1.f / 25.f);
    }
}

// -------- h2[m] += z[p] over the pair list (atomic) -----------------------
__global__ __launch_bounds__(256) void hg9_gscatter(const unsigned int* pairs,
                                                    const float* z, float* h2) {
    int idx = (blockIdx.x * 256 + threadIdx.x) >> 6;
    int lane = threadIdx.x & 63;
    if (idx >= NPAIRS) return;
    unsigned int pk = pairs[idx];
    int b = pk >> 24;
    if (b >= HB) return;                         // defensive (poison)
    int p = (pk >> 12) & 0xFFF, m = pk & 0xFFF;
    atomicAdd(&h2[(b * HN + m) * HC + lane], z[(b * HE + p) * HC + lane]);
}

// -------- add window contributions + final Dv^-1/2 scale ------------------
__global__ __launch_bounds__(256) void hg9_gfinish(const float* z, const int* indeg, float* h2) {
    int wave = (blockIdx.x * 256 + threadIdx.x) >> 6;  // one wave per (b, node)
    int lane = threadIdx.x & 63;
    int b = wave / HN, n = wave % HN;
    int g = b * HN + n;
    float acc = h2[g * HC + lane];
    int r = n / HL, c = n % HL;
    int rlo = hg9_lo(r), rhi = hg9_hi(r), clo = hg9_lo(c), chi = hg9_hi(c);
    for (int wr = rlo; wr <= rhi; wr++)
        for (int wc = clo; wc <= chi; wc++)
            acc += z[(b * HE + HN + wr * HW + wc) * HC + lane];
    int dvn = max(indeg[g] + max(0, rhi - rlo + 1) * max(0, chi - clo + 1), 1);
    h2[g * HC + lane] = acc * rsqrtf((float)dvn);
}

// -------- BN stats --------------------------------------------------------
__global__ __launch_bounds__(256) void hg9_bnstats(const float* h2, float* bnsum, float* bnss) {
    int t = threadIdx.x;
    int c = t & 63, rg = t >> 6;
    int row0 = blockIdx.x * 36;      // 256 blocks * 36 rows = 9216
    float s = 0.f, ss = 0.f;
    for (int r = rg; r < 36; r += 4) {
        float v = h2[(row0 + r) * HC + c];
        s += v; ss += v * v;
    }
    __shared__ float ls[256], lss[256];
    ls[t] = s; lss[t] = ss;
    __syncthreads();
    if (t < 64) {
        s  = ls[t]  + ls[t + 64]  + ls[t + 128]  + ls[t + 192];
        ss = lss[t] + lss[t + 64] + lss[t + 128] + lss[t + 192];
        atomicAdd(&bnsum[t], s);
        atomicAdd(&bnss[t], ss);
    }
}

// -------- BN + ReLU + residual --------------------------------------------
__global__ __launch_bounds__(256) void hg9_final(const float* h2, const float* x,
                                                 const float* gamma, const float* beta,
                                                 const float* bnsum, const float* bnss,
                                                 float* out) {
    int i = blockIdx.x * 256 + threadIdx.x;
    int c = i & 63;
    const float M = (float)(HB * HN);
    float mean = bnsum[c] / M;
    float var  = bnss[c] / M - mean * mean;
    float inv  = rsqrtf(var + 1e-5f);
    float h = gamma[c] * (h2[i] - mean) * inv + beta[c];
    out[i] = fmaxf(h, 0.f) + x[i];
}

extern "C" void kernel_launch(void* const* d_in, const int* in_sizes, int n_in,
                              void* d_out, int out_size, void* d_ws, size_t ws_size,
                              hipStream_t stream) {
    const float* x     = (const float*)d_in[0];
    const float* W     = (const float*)d_in[1];
    const float* bias  = (const float*)d_in[2];
    const float* gamma = (const float*)d_in[3];
    const float* beta  = (const float*)d_in[4];
    float* out = (float*)d_out;
    (void)in_sizes; (void)n_in;

    char* ws = (char*)d_ws;
    size_t off = 0;
    float*        xsq     = (float*)(ws + off);        off += (size_t)HB * HN * 4;
    float*        h1      = (float*)(ws + off);        off += (size_t)HB * HN * HC * 4;
    float*        h2      = (float*)(ws + off);        off += (size_t)HB * HN * HC * 4;
    int*          Dv      = (int*)(ws + off);          off += (size_t)HB * HN * 4;
    int*          indeg   = (int*)(ws + off);          off += (size_t)HB * HN * 4;
    unsigned int* pairs   = (unsigned int*)(ws + off); off += (size_t)NPAIRS * 4;
    float*        bnsum   = (float*)(ws + off);        off += 256;
    float*        bnss    = (float*)(ws + off);        off += 256;
    int*          paircnt = (int*)(ws + off);          off += 256;
    float*        xT      = (float*)(ws + off);        // z aliases xT (dead after kNN)
    float*        z       = (float*)(ws + off);
    off += (size_t)HB * HE * HC * 4;   // max(xT, z) = z

    if (ws_size < off) {
        hg9_sentinel<<<(out_size + 255) / 256, 256, 0, stream>>>(out, out_size);
        return;
    }

    const int EDGE_WAVES = NPAIRS + HB * HE2;    // 103312, divisible by 4

    hg9_init<<<(HB * HN + 255) / 256, 256, 0, stream>>>(Dv, indeg, paircnt, bnsum, bnss);
    hg9_linear<<<HB * HN, 64, 0, stream>>>(x, W, bias, h1, xsq, xT);
    hg9_knn_count<<<HB * (HN / HRPB), 256, 0, stream>>>(xT, xsq, Dv, indeg, pairs, paircnt);
    hg9_knn_select<<<HB * (HN / HRPB), 256, 0, stream>>>(xT, xsq, Dv, indeg, pairs, paircnt);
    hg9_scale<<<(HB * HN * HC) / 256, 256, 0, stream>>>(h1, indeg);
    hg9_zero<<<(HB * HN * HC) / 256, 256, 0, stream>>>(z, h2);
    hg9_edge<<<EDGE_WAVES / 4, 256, 0, stream>>>(pairs, Dv, h1, z);
    hg9_gscatter<<<(NPAIRS * 64) / 256, 256, 0, stream>>>(pairs, z, h2);
    hg9_gfinish<<<(HB * HN) / 4, 256, 0, stream>>>(z, indeg, h2);
    hg9_bnstats<<<256, 256, 0, stream>>>(h2, bnsum, bnss);
    hg9_final<<<(HB * HN * HC) / 256, 256, 0, stream>>>(h2, x, gamma, beta, bnsum, bnss, out);
}

// Round 10
// 830.130 us; speedup vs baseline: 1.0087x; 1.0087x over previous
//
#include <hip/hip_runtime.h>

// HGNN layer, v10 — fp32. kNN selection rebuilt around a per-lane sorted
// top-4 register cache: per extraction only a 6-stage shfl butterfly over
// the 64 cache heads + a shift in the winner lane (rare filtered refill).
// v8's everyone-scans-36-u64-per-extraction loop is gone. B=4, N=2304, C=64.

#define HB    4
#define HN    2304
#define HC    64
#define HK    11             // K_NEIGS + 1
#define HL    48
#define HW    22             // windows per dim
#define HE2   484            // 22*22 local edges
#define HE    (HN + HE2)
#define HRPB  4              // rows per block == waves per block
#define HTS   768            // m-tile (3 tiles); 768 = 3*256
#define NSLOT 36             // keys per lane (2304/64)
#define NPAIRS (HB * HK * HN)   // sum of Dv == 11*N per batch, exact

__global__ void hg10_sentinel(float* out, int n) {
    int i = blockIdx.x * 256 + threadIdx.x;
    if (i < n) out[i] = 12345.0f;
}

__global__ void hg10_init(int* Dv, int* indeg, int* paircnt, float* bnsum, float* bnss) {
    int i = blockIdx.x * 256 + threadIdx.x;
    if (i < HB * HN) { Dv[i] = 0; indeg[i] = 0; }
    if (i == 0) *paircnt = 0;
    if (i < HC) { bnsum[i] = 0.f; bnss[i] = 0.f; }
}

// -------- linear h1 = x W^T + b, xsq, f32 transpose -----------------------
__global__ __launch_bounds__(64) void hg10_linear(const float* x, const float* W,
                                                  const float* bias, float* h1,
                                                  float* xsq, float* xT) {
    int row = blockIdx.x;            // 0..B*N-1
    int t = threadIdx.x;
    __shared__ float xr[HC];
    float v = x[row * HC + t];
    xr[t] = v;
    __syncthreads();
    float sq = v * v;
    #pragma unroll
    for (int o = 32; o > 0; o >>= 1) sq += __shfl_xor(sq, o);
    if (t == 0) xsq[row] = sq;
    int b = row / HN, n = row % HN;
    xT[(b * HC + t) * HN + n] = v;
    float acc = bias[t];
    #pragma unroll 8
    for (int c = 0; c < HC; c++) acc += xr[c] * W[t * HC + c];
    h1[row * HC + t] = acc;
}

__device__ __forceinline__ unsigned long long hg10_wave_min(unsigned long long v) {
    #pragma unroll
    for (int o = 32; o > 0; o >>= 1) {
        unsigned long long ov = __shfl_xor(v, o);
        if (ov < v) v = ov;
    }
    return v;
}

// sorted-insert x into ascending (c0..c3), dropping the largest
#define HG10_INSERT(x)                                                   \
    {                                                                    \
        unsigned long long x_ = (x), n_;                                 \
        n_ = c0 < x_ ? c0 : x_; x_ = c0 < x_ ? x_ : c0; c0 = n_;         \
        n_ = c1 < x_ ? c1 : x_; x_ = c1 < x_ ? x_ : c1; c1 = n_;         \
        n_ = c2 < x_ ? c2 : x_; x_ = c2 < x_ ? x_ : c2; c2 = n_;         \
        if (x_ < c3) c3 = x_;                                            \
    }

// -------- kNN: tiled block distances, per-lane top-4 cache selection ------
// SEL=0: pick 11 nearest per row (incl self), count Dv[neighbor].
// SEL=1: pick Dv[row] nearest, emit (b,p,m) pairs, count node in-degree.
// Layout: lane's slot s holds node m = (s<<6)|lane. Packed key: (key<<12)|m,
// totally ordered (m distinct) == reference (value, lowest-index) order.
__device__ __forceinline__ void hg10_knn_body(const float* xT, const float* xsq,
                                              int* Dv, int* indeg,
                                              unsigned int* pairs, int* paircnt,
                                              int SEL) {
    __shared__ float dtile[HRPB][HTS];   // 12 KB
    __shared__ float xr[HRPB][HC];       // 1 KB
    const int t = threadIdx.x;
    const int b = blockIdx.x / (HN / HRPB);
    const int n0 = (blockIdx.x % (HN / HRPB)) * HRPB;
    const int r = t >> 6;
    const int lane = t & 63;
    xr[r][lane] = xT[(b * HC + lane) * HN + n0 + r];
    __syncthreads();
    float xs[HRPB];
    #pragma unroll
    for (int q = 0; q < HRPB; q++) xs[q] = xsq[b * HN + n0 + q];

    const unsigned long long CINF = ~0ull;
    unsigned int key[NSLOT];
    unsigned long long c0 = CINF, c1 = CINF, c2 = CINF, c3 = CINF;

    #pragma unroll
    for (int tt = 0; tt < HN / HTS; tt++) {       // 3 tiles
        for (int mi = t; mi < HTS; mi += 256) {   // 3 iters; same fp order as v8
            int m = tt * HTS + mi;
            float dot0 = 0.f, dot1 = 0.f, dot2 = 0.f, dot3 = 0.f;
            #pragma unroll 8
            for (int c = 0; c < HC; c++) {
                float xv = xT[(b * HC + c) * HN + m];
                dot0 += xr[0][c] * xv;
                dot1 += xr[1][c] * xv;
                dot2 += xr[2][c] * xv;
                dot3 += xr[3][c] * xv;
            }
            float xsm = xsq[b * HN + m];
            dtile[0][mi] = xs[0] + xsm - 2.f * dot0;
            dtile[1][mi] = xs[1] + xsm - 2.f * dot1;
            dtile[2][mi] = xs[2] + xsm - 2.f * dot2;
            dtile[3][mi] = xs[3] + xsm - 2.f * dot3;
        }
        __syncthreads();
        #pragma unroll
        for (int j = 0; j < HTS / 64; j++) {      // fold 12 slots into registers
            int s = tt * (HTS / 64) + j;
            float f = dtile[r][(j << 6) + lane];
            unsigned int ub = __float_as_uint(f);
            unsigned int k = ub ^ (((unsigned int)(((int)ub) >> 31)) | 0x80000000u);
            key[s] = k;
            unsigned long long pk =
                ((unsigned long long)k << 12) | (unsigned)((s << 6) | lane);
            HG10_INSERT(pk);
        }
        __syncthreads();
    }

    // ---- selection: one wave per row, no barriers.
    const int p = n0 + r;
    const int kk = SEL ? max(Dv[b * HN + p], 1) : HK;
    int base = 0;
    if (SEL) {                                   // reserve kk pair slots once
        if (lane == 0) base = atomicAdd(paircnt, kk);
        base = __shfl(base, 0);
    }
    for (int j = 0; j < kk; j++) {
        unsigned long long best = hg10_wave_min(c0);
        bool win = (c0 == best);                 // unique winner (packed distinct)
        if (win) {
            c0 = c1; c1 = c2; c2 = c3; c3 = CINF;
            if (c0 == CINF) {                    // rare refill: next 4 > best
                #pragma unroll
                for (int s = 0; s < NSLOT; s++) {
                    unsigned long long pk =
                        ((unsigned long long)key[s] << 12) | (unsigned)((s << 6) | lane);
                    if (pk > best) HG10_INSERT(pk);
                }
            }
        }
        if (lane == 0) {
            int bi = (int)(best & 0xFFFu);
            if (SEL) {
                atomicAdd(&indeg[b * HN + bi], 1);
                pairs[base + j] = ((unsigned)b << 24) | ((unsigned)p << 12) | (unsigned)bi;
            } else {
                atomicAdd(&Dv[b * HN + bi], 1);
            }
        }
    }
}

__global__ __launch_bounds__(256) void hg10_knn_count(const float* xT, const float* xsq,
                                                      int* Dv, int* indeg,
                                                      unsigned int* pairs, int* paircnt) {
    hg10_knn_body(xT, xsq, Dv, indeg, pairs, paircnt, 0);
}

__global__ __launch_bounds__(256) void hg10_knn_select(const float* xT, const float* xsq,
                                                       int* Dv, int* indeg,
                                                       unsigned int* pairs, int* paircnt) {
    hg10_knn_body(xT, xsq, Dv, indeg, pairs, paircnt, 1);
}

__device__ __forceinline__ int hg10_lo(int rc) { return max(0, (rc - 3) / 2); }
__device__ __forceinline__ int hg10_hi(int rc) { return min(HW - 1, rc / 2); }

// -------- y = Dv^-1/2 * h1 (in place) -------------------------------------
__global__ __launch_bounds__(256) void hg10_scale(float* h1, const int* indeg) {
    int i = blockIdx.x * 256 + threadIdx.x;
    int node = i >> 6;
    int n = node % HN;
    int r = n / HL, c = n % HL;
    int cover = max(0, hg10_hi(r) - hg10_lo(r) + 1) * max(0, hg10_hi(c) - hg10_lo(c) + 1);
    int dvn = max(indeg[node] + cover, 1);
    h1[i] *= rsqrtf((float)dvn);
}

// -------- zero z (kNN-edge part) and h2, one kernel -----------------------
__global__ void hg10_zero(float* z, float* h2) {
    int i = blockIdx.x * 256 + threadIdx.x;      // over B*N*C
    int b = i / (HN * HC), rem = i % (HN * HC);
    z[b * HE * HC + rem] = 0.f;                  // window part written by edge kernel
    h2[i] = 0.f;
}

// -------- fused edge kernel: kNN scatter + window means -------------------
__global__ __launch_bounds__(256) void hg10_edge(const unsigned int* pairs, const int* Dv,
                                                 const float* y, float* z) {
    int wv = (blockIdx.x * 256 + threadIdx.x) >> 6;
    int lane = threadIdx.x & 63;
    if (wv < NPAIRS) {
        unsigned int pk = pairs[wv];
        int b = pk >> 24;
        if (b >= HB) return;                     // defensive (poison)
        int p = (pk >> 12) & 0xFFF, m = pk & 0xFFF;
        float invde = 1.f / (float)max(Dv[b * HN + p], 1);
        atomicAdd(&z[(b * HE + p) * HC + lane], y[(b * HN + m) * HC + lane] * invde);
    } else {
        int w2 = wv - NPAIRS;
        if (w2 >= HB * HE2) return;
        int b = w2 / HE2, w = w2 % HE2;
        int wr = w / HW, wc = w % HW;
        float acc = 0.f;
        #pragma unroll
        for (int i = 0; i < 5; i++)
            #pragma unroll
            for (int j = 0; j < 5; j++)
                acc += y[(b * HN + (wr * 2 + i) * HL + wc * 2 + j) * HC + lane];
        z[(b * HE + HN + w) * HC + lane] = acc * (1.f / 25.f);
    }
}

// -------- h2[m] += z[p] over the pair list (atomic) -----------------------
__global__ __launch_bounds__(256) void hg10_gscatter(const unsigned int* pairs,
                                                     const float* z, float* h2) {
    int idx = (blockIdx.x * 256 + threadIdx.x) >> 6;
    int lane = threadIdx.x & 63;
    if (idx >= NPAIRS) return;
    unsigned int pk = pairs[idx];
    int b = pk >> 24;
    if (b >= HB) return;                         // defensive (poison)
    int p = (pk >> 12) & 0xFFF, m = pk & 0xFFF;
    atomicAdd(&h2[(b * HN + m) * HC + lane], z[(b * HE + p) * HC + lane]);
}

// -------- add window contributions + final Dv^-1/2 scale ------------------
__global__ __launch_bounds__(256) void hg10_gfinish(const float* z, const int* indeg, float* h2) {
    int wave = (blockIdx.x * 256 + threadIdx.x) >> 6;  // one wave per (b, node)
    int lane = threadIdx.x & 63;
    int b = wave / HN, n = wave % HN;
    int g = b * HN + n;
    float acc = h2[g * HC + lane];
    int r = n / HL, c = n % HL;
    int rlo = hg10_lo(r), rhi = hg10_hi(r), clo = hg10_lo(c), chi = hg10_hi(c);
    for (int wr = rlo; wr <= rhi; wr++)
        for (int wc = clo; wc <= chi; wc++)
            acc += z[(b * HE + HN + wr * HW + wc) * HC + lane];
    int dvn = max(indeg[g] + max(0, rhi - rlo + 1) * max(0, chi - clo + 1), 1);
    h2[g * HC + lane] = acc * rsqrtf((float)dvn);
}

// -------- BN stats --------------------------------------------------------
__global__ __launch_bounds__(256) void hg10_bnstats(const float* h2, float* bnsum, float* bnss) {
    int t = threadIdx.x;
    int c = t & 63, rg = t >> 6;
    int row0 = blockIdx.x * 36;      // 256 blocks * 36 rows = 9216
    float s = 0.f, ss = 0.f;
    for (int r = rg; r < 36; r += 4) {
        float v = h2[(row0 + r) * HC + c];
        s += v; ss += v * v;
    }
    __shared__ float ls[256], lss[256];
    ls[t] = s; lss[t] = ss;
    __syncthreads();
    if (t < 64) {
        s  = ls[t]  + ls[t + 64]  + ls[t + 128]  + ls[t + 192];
        ss = lss[t] + lss[t + 64] + lss[t + 128] + lss[t + 192];
        atomicAdd(&bnsum[t], s);
        atomicAdd(&bnss[t], ss);
    }
}

// -------- BN + ReLU + residual --------------------------------------------
__global__ __launch_bounds__(256) void hg10_final(const float* h2, const float* x,
                                                  const float* gamma, const float* beta,
                                                  const float* bnsum, const float* bnss,
                                                  float* out) {
    int i = blockIdx.x * 256 + threadIdx.x;
    int c = i & 63;
    const float M = (float)(HB * HN);
    float mean = bnsum[c] / M;
    float var  = bnss[c] / M - mean * mean;
    float inv  = rsqrtf(var + 1e-5f);
    float h = gamma[c] * (h2[i] - mean) * inv + beta[c];
    out[i] = fmaxf(h, 0.f) + x[i];
}

extern "C" void kernel_launch(void* const* d_in, const int* in_sizes, int n_in,
                              void* d_out, int out_size, void* d_ws, size_t ws_size,
                              hipStream_t stream) {
    const float* x     = (const float*)d_in[0];
    const float* W     = (const float*)d_in[1];
    const float* bias  = (const float*)d_in[2];
    const float* gamma = (const float*)d_in[3];
    const float* beta  = (const float*)d_in[4];
    float* out = (float*)d_out;
    (void)in_sizes; (void)n_in;

    char* ws = (char*)d_ws;
    size_t off = 0;
    float*        xsq     = (float*)(ws + off);        off += (size_t)HB * HN * 4;
    float*        h1      = (float*)(ws + off);        off += (size_t)HB * HN * HC * 4;
    float*        h2      = (float*)(ws + off);        off += (size_t)HB * HN * HC * 4;
    int*          Dv      = (int*)(ws + off);          off += (size_t)HB * HN * 4;
    int*          indeg   = (int*)(ws + off);          off += (size_t)HB * HN * 4;
    unsigned int* pairs   = (unsigned int*)(ws + off); off += (size_t)NPAIRS * 4;
    float*        bnsum   = (float*)(ws + off);        off += 256;
    float*        bnss    = (float*)(ws + off);        off += 256;
    int*          paircnt = (int*)(ws + off);          off += 256;
    float*        xT      = (float*)(ws + off);        // z aliases xT (dead after kNN)
    float*        z       = (float*)(ws + off);
    off += (size_t)HB * HE * HC * 4;   // max(xT, z) = z

    if (ws_size < off) {
        hg10_sentinel<<<(out_size + 255) / 256, 256, 0, stream>>>(out, out_size);
        return;
    }

    const int EDGE_WAVES = NPAIRS + HB * HE2;    // 103312, divisible by 4

    hg10_init<<<(HB * HN + 255) / 256, 256, 0, stream>>>(Dv, indeg, paircnt, bnsum, bnss);
    hg10_linear<<<HB * HN, 64, 0, stream>>>(x, W, bias, h1, xsq, xT);
    hg10_knn_count<<<HB * (HN / HRPB), 256, 0, stream>>>(xT, xsq, Dv, indeg, pairs, paircnt);
    hg10_knn_select<<<HB * (HN / HRPB), 256, 0, stream>>>(xT, xsq, Dv, indeg, pairs, paircnt);
    hg10_scale<<<(HB * HN * HC) / 256, 256, 0, stream>>>(h1, indeg);
    hg10_zero<<<(HB * HN * HC) / 256, 256, 0, stream>>>(z, h2);
    hg10_edge<<<EDGE_WAVES / 4, 256, 0, stream>>>(pairs, Dv, h1, z);
    hg10_gscatter<<<(NPAIRS * 64) / 256, 256, 0, stream>>>(pairs, z, h2);
    hg10_gfinish<<<(HB * HN) / 4, 256, 0, stream>>>(z, indeg, h2);
    hg10_bnstats<<<256, 256, 0, stream>>>(h2, bnsum, bnss);
    hg10_final<<<(HB * HN * HC) / 256, 256, 0, stream>>>(h2, x, gamma, beta, bnsum, bnss, out);
}

// Round 11
// 601.256 us; speedup vs baseline: 1.3927x; 1.3807x over previous
//
#include <hip/hip_runtime.h>

// HGNN layer, v11 — fp32. Decisive split of kNN cost: count pass (v8-style
// untiled distance phase, fastest measured) stores bit-exact packed keys to
// global (85 MB); select pass loads keys (no distance recompute, no LDS).
// Host falls back to full-recompute select if ws_size < ~93 MB.

#define HB    4
#define HN    2304
#define HC    64
#define HK    11             // K_NEIGS + 1
#define HL    48
#define HW    22             // windows per dim
#define HE2   484            // 22*22 local edges
#define HE    (HN + HE2)
#define HRPB  4              // rows per block == waves per block
#define NSLOT 36             // keys per lane (2304/64)
#define NPAIRS (HB * HK * HN)   // sum of Dv == 11*N per batch, exact

__global__ void hg11_sentinel(float* out, int n) {
    int i = blockIdx.x * 256 + threadIdx.x;
    if (i < n) out[i] = 12345.0f;
}

__global__ void hg11_init(int* Dv, int* indeg, int* paircnt, float* bnsum, float* bnss) {
    int i = blockIdx.x * 256 + threadIdx.x;
    if (i < HB * HN) { Dv[i] = 0; indeg[i] = 0; }
    if (i == 0) *paircnt = 0;
    if (i < HC) { bnsum[i] = 0.f; bnss[i] = 0.f; }
}

// -------- linear h1 = x W^T + b, xsq, f32 transpose -----------------------
__global__ __launch_bounds__(64) void hg11_linear(const float* x, const float* W,
                                                  const float* bias, float* h1,
                                                  float* xsq, float* xT) {
    int row = blockIdx.x;            // 0..B*N-1
    int t = threadIdx.x;
    __shared__ float xr[HC];
    float v = x[row * HC + t];
    xr[t] = v;
    __syncthreads();
    float sq = v * v;
    #pragma unroll
    for (int o = 32; o > 0; o >>= 1) sq += __shfl_xor(sq, o);
    if (t == 0) xsq[row] = sq;
    int b = row / HN, n = row % HN;
    xT[(b * HC + t) * HN + n] = v;
    float acc = bias[t];
    #pragma unroll 8
    for (int c = 0; c < HC; c++) acc += xr[c] * W[t * HC + c];
    h1[row * HC + t] = acc;
}

__device__ __forceinline__ unsigned long long hg11_wave_min(unsigned long long v) {
    #pragma unroll
    for (int o = 32; o > 0; o >>= 1) {
        unsigned long long ov = __shfl_xor(v, o);
        if (ov < v) v = ov;
    }
    return v;
}

// sorted-insert x into ascending (c0..c3), dropping the largest
#define HG11_INSERT(x)                                                   \
    {                                                                    \
        unsigned long long x_ = (x), n_;                                 \
        n_ = c0 < x_ ? c0 : x_; x_ = c0 < x_ ? x_ : c0; c0 = n_;         \
        n_ = c1 < x_ ? c1 : x_; x_ = c1 < x_ ? x_ : c1; c1 = n_;         \
        n_ = c2 < x_ ? c2 : x_; x_ = c2 < x_ ? x_ : c2; c2 = n_;         \
        if (x_ < c3) c3 = x_;                                            \
    }

// extraction loop: pops kk smallest packed keys in exact ascending order.
// key[NSLOT] per lane; slot s of lane l is node m = (s<<6)|l.
#define HG11_EXTRACT(kk, EMIT)                                                     \
    {                                                                              \
        const unsigned long long CINF_ = ~0ull;                                    \
        for (int j = 0; j < (kk); j++) {                                           \
            unsigned long long best = hg11_wave_min(c0);                           \
            if (c0 == best) {                                                      \
                c0 = c1; c1 = c2; c2 = c3; c3 = CINF_;                             \
                if (c0 == CINF_) {                                                 \
                    _Pragma("unroll")                                              \
                    for (int s = 0; s < NSLOT; s++) {                              \
                        unsigned long long pk =                                    \
                            ((unsigned long long)key[s] << 12) |                   \
                            (unsigned)((s << 6) | lane);                           \
                        if (pk > best) HG11_INSERT(pk);                            \
                    }                                                              \
                }                                                                  \
            }                                                                      \
            if (lane == 0) { int bi = (int)(best & 0xFFFu); EMIT; }                \
        }                                                                          \
    }

// -------- kNN count: untiled distance phase (v8 layout) + key store -------
__global__ __launch_bounds__(256) void hg11_knn_count(const float* xT, const float* xsq,
                                                      int* Dv, unsigned int* kcache,
                                                      int storekeys) {
    __shared__ float d[HRPB][HN];      // 36 KB
    __shared__ float xr[HRPB][HC];
    const int t = threadIdx.x;
    const int b = blockIdx.x / (HN / HRPB);
    const int n0 = (blockIdx.x % (HN / HRPB)) * HRPB;
    const int r = t >> 6;
    const int lane = t & 63;
    xr[r][lane] = xT[(b * HC + lane) * HN + n0 + r];
    __syncthreads();
    float xs[HRPB];
    #pragma unroll
    for (int q = 0; q < HRPB; q++) xs[q] = xsq[b * HN + n0 + q];
    for (int m = t; m < HN; m += 256) {          // 9 iterations
        float dot0 = 0.f, dot1 = 0.f, dot2 = 0.f, dot3 = 0.f;
        #pragma unroll 8
        for (int c = 0; c < HC; c++) {
            float xv = xT[(b * HC + c) * HN + m];
            dot0 += xr[0][c] * xv;
            dot1 += xr[1][c] * xv;
            dot2 += xr[2][c] * xv;
            dot3 += xr[3][c] * xv;
        }
        float xsm = xsq[b * HN + m];
        d[0][m] = xs[0] + xsm - 2.f * dot0;
        d[1][m] = xs[1] + xsm - 2.f * dot1;
        d[2][m] = xs[2] + xsm - 2.f * dot2;
        d[3][m] = xs[3] + xsm - 2.f * dot3;
    }
    __syncthreads();

    const int p = n0 + r;
    const unsigned long long CINF = ~0ull;
    unsigned int key[NSLOT];
    unsigned long long c0 = CINF, c1 = CINF, c2 = CINF, c3 = CINF;
    const int rowbase = (b * HN + p) * NSLOT;
    #pragma unroll
    for (int s = 0; s < NSLOT; s++) {
        float f = d[r][(s << 6) | lane];
        unsigned int ub = __float_as_uint(f);
        unsigned int k = ub ^ (((unsigned int)(((int)ub) >> 31)) | 0x80000000u);
        key[s] = k;
        if (storekeys) kcache[(rowbase + s) * 64 + lane] = k;
        unsigned long long pk =
            ((unsigned long long)k << 12) | (unsigned)((s << 6) | lane);
        HG11_INSERT(pk);
    }
    HG11_EXTRACT(HK, atomicAdd(&Dv[b * HN + bi], 1));
}

// -------- kNN select, cached keys: no distance phase, no LDS --------------
__global__ __launch_bounds__(256) void hg11_knn_sel_cached(const unsigned int* kcache,
                                                           const int* Dv, int* indeg,
                                                           unsigned int* pairs, int* paircnt) {
    const int t = threadIdx.x;
    const int lane = t & 63;
    const int gw = blockIdx.x * HRPB + (t >> 6);   // global row 0..B*N-1
    const int b = gw / HN, p = gw % HN;
    const unsigned long long CINF = ~0ull;
    unsigned int key[NSLOT];
    unsigned long long c0 = CINF, c1 = CINF, c2 = CINF, c3 = CINF;
    const int rowbase = gw * NSLOT;
    #pragma unroll
    for (int s = 0; s < NSLOT; s++) {
        unsigned int k = kcache[(rowbase + s) * 64 + lane];
        key[s] = k;
        unsigned long long pk =
            ((unsigned long long)k << 12) | (unsigned)((s << 6) | lane);
        HG11_INSERT(pk);
    }
    const int kk = max(Dv[gw], 1);
    int base = 0;
    if (lane == 0) base = atomicAdd(paircnt, kk);
    base = __shfl(base, 0);
    HG11_EXTRACT(kk,
        { atomicAdd(&indeg[b * HN + bi], 1);
          pairs[base + j] = ((unsigned)b << 24) | ((unsigned)p << 12) | (unsigned)bi; });
}

// -------- kNN select, full recompute (fallback when ws too small) ---------
__global__ __launch_bounds__(256) void hg11_knn_sel_full(const float* xT, const float* xsq,
                                                         const int* Dv, int* indeg,
                                                         unsigned int* pairs, int* paircnt) {
    __shared__ float d[HRPB][HN];
    __shared__ float xr[HRPB][HC];
    const int t = threadIdx.x;
    const int b = blockIdx.x / (HN / HRPB);
    const int n0 = (blockIdx.x % (HN / HRPB)) * HRPB;
    const int r = t >> 6;
    const int lane = t & 63;
    xr[r][lane] = xT[(b * HC + lane) * HN + n0 + r];
    __syncthreads();
    float xs[HRPB];
    #pragma unroll
    for (int q = 0; q < HRPB; q++) xs[q] = xsq[b * HN + n0 + q];
    for (int m = t; m < HN; m += 256) {
        float dot0 = 0.f, dot1 = 0.f, dot2 = 0.f, dot3 = 0.f;
        #pragma unroll 8
        for (int c = 0; c < HC; c++) {
            float xv = xT[(b * HC + c) * HN + m];
            dot0 += xr[0][c] * xv;
            dot1 += xr[1][c] * xv;
            dot2 += xr[2][c] * xv;
            dot3 += xr[3][c] * xv;
        }
        float xsm = xsq[b * HN + m];
        d[0][m] = xs[0] + xsm - 2.f * dot0;
        d[1][m] = xs[1] + xsm - 2.f * dot1;
        d[2][m] = xs[2] + xsm - 2.f * dot2;
        d[3][m] = xs[3] + xsm - 2.f * dot3;
    }
    __syncthreads();
    const int p = n0 + r;
    const unsigned long long CINF = ~0ull;
    unsigned int key[NSLOT];
    unsigned long long c0 = CINF, c1 = CINF, c2 = CINF, c3 = CINF;
    #pragma unroll
    for (int s = 0; s < NSLOT; s++) {
        float f = d[r][(s << 6) | lane];
        unsigned int ub = __float_as_uint(f);
        unsigned int k = ub ^ (((unsigned int)(((int)ub) >> 31)) | 0x80000000u);
        key[s] = k;
        unsigned long long pk =
            ((unsigned long long)k << 12) | (unsigned)((s << 6) | lane);
        HG11_INSERT(pk);
    }
    const int kk = max(Dv[b * HN + p], 1);
    int base = 0;
    if (lane == 0) base = atomicAdd(paircnt, kk);
    base = __shfl(base, 0);
    HG11_EXTRACT(kk,
        { atomicAdd(&indeg[b * HN + bi], 1);
          pairs[base + j] = ((unsigned)b << 24) | ((unsigned)p << 12) | (unsigned)bi; });
}

__device__ __forceinline__ int hg11_lo(int rc) { return max(0, (rc - 3) / 2); }
__device__ __forceinline__ int hg11_hi(int rc) { return min(HW - 1, rc / 2); }

// -------- y = Dv^-1/2 * h1 (in place) -------------------------------------
__global__ __launch_bounds__(256) void hg11_scale(float* h1, const int* indeg) {
    int i = blockIdx.x * 256 + threadIdx.x;
    int node = i >> 6;
    int n = node % HN;
    int r = n / HL, c = n % HL;
    int cover = max(0, hg11_hi(r) - hg11_lo(r) + 1) * max(0, hg11_hi(c) - hg11_lo(c) + 1);
    int dvn = max(indeg[node] + cover, 1);
    h1[i] *= rsqrtf((float)dvn);
}

// -------- zero z (kNN-edge part) and h2 -----------------------------------
__global__ void hg11_zero(float* z, float* h2) {
    int i = blockIdx.x * 256 + threadIdx.x;      // over B*N*C
    int b = i / (HN * HC), rem = i % (HN * HC);
    z[b * HE * HC + rem] = 0.f;
    h2[i] = 0.f;
}

// -------- fused edge kernel: kNN scatter + window means -------------------
__global__ __launch_bounds__(256) void hg11_edge(const unsigned int* pairs, const int* Dv,
                                                 const float* y, float* z) {
    int wv = (blockIdx.x * 256 + threadIdx.x) >> 6;
    int lane = threadIdx.x & 63;
    if (wv < NPAIRS) {
        unsigned int pk = pairs[wv];
        int b = pk >> 24;
        if (b >= HB) return;                     // defensive (poison)
        int p = (pk >> 12) & 0xFFF, m = pk & 0xFFF;
        float invde = 1.f / (float)max(Dv[b * HN + p], 1);
        atomicAdd(&z[(b * HE + p) * HC + lane], y[(b * HN + m) * HC + lane] * invde);
    } else {
        int w2 = wv - NPAIRS;
        if (w2 >= HB * HE2) return;
        int b = w2 / HE2, w = w2 % HE2;
        int wr = w / HW, wc = w % HW;
        float acc = 0.f;
        #pragma unroll
        for (int i = 0; i < 5; i++)
            #pragma unroll
            for (int j = 0; j < 5; j++)
                acc += y[(b * HN + (wr * 2 + i) * HL + wc * 2 + j) * HC + lane];
        z[(b * HE + HN + w) * HC + lane] = acc * (1.f / 25.f);
    }
}

// -------- h2[m] += z[p] over the pair list (atomic) -----------------------
__global__ __launch_bounds__(256) void hg11_gscatter(const unsigned int* pairs,
                                                     const float* z, float* h2) {
    int idx = (blockIdx.x * 256 + threadIdx.x) >> 6;
    int lane = threadIdx.x & 63;
    if (idx >= NPAIRS) return;
    unsigned int pk = pairs[idx];
    int b = pk >> 24;
    if (b >= HB) return;                         // defensive (poison)
    int p = (pk >> 12) & 0xFFF, m = pk & 0xFFF;
    atomicAdd(&h2[(b * HN + m) * HC + lane], z[(b * HE + p) * HC + lane]);
}

// -------- add window contributions + final Dv^-1/2 scale ------------------
__global__ __launch_bounds__(256) void hg11_gfinish(const float* z, const int* indeg, float* h2) {
    int wave = (blockIdx.x * 256 + threadIdx.x) >> 6;  // one wave per (b, node)
    int lane = threadIdx.x & 63;
    int b = wave / HN, n = wave % HN;
    int g = b * HN + n;
    float acc = h2[g * HC + lane];
    int r = n / HL, c = n % HL;
    int rlo = hg11_lo(r), rhi = hg11_hi(r), clo = hg11_lo(c), chi = hg11_hi(c);
    for (int wr = rlo; wr <= rhi; wr++)
        for (int wc = clo; wc <= chi; wc++)
            acc += z[(b * HE + HN + wr * HW + wc) * HC + lane];
    int dvn = max(indeg[g] + max(0, rhi - rlo + 1) * max(0, chi - clo + 1), 1);
    h2[g * HC + lane] = acc * rsqrtf((float)dvn);
}

// -------- BN stats --------------------------------------------------------
__global__ __launch_bounds__(256) void hg11_bnstats(const float* h2, float* bnsum, float* bnss) {
    int t = threadIdx.x;
    int c = t & 63, rg = t >> 6;
    int row0 = blockIdx.x * 36;      // 256 blocks * 36 rows = 9216
    float s = 0.f, ss = 0.f;
    for (int r = rg; r < 36; r += 4) {
        float v = h2[(row0 + r) * HC + c];
        s += v; ss += v * v;
    }
    __shared__ float ls[256], lss[256];
    ls[t] = s; lss[t] = ss;
    __syncthreads();
    if (t < 64) {
        s  = ls[t]  + ls[t + 64]  + ls[t + 128]  + ls[t + 192];
        ss = lss[t] + lss[t + 64] + lss[t + 128] + lss[t + 192];
        atomicAdd(&bnsum[t], s);
        atomicAdd(&bnss[t], ss);
    }
}

// -------- BN + ReLU + residual --------------------------------------------
__global__ __launch_bounds__(256) void hg11_final(const float* h2, const float* x,
                                                  const float* gamma, const float* beta,
                                                  const float* bnsum, const float* bnss,
                                                  float* out) {
    int i = blockIdx.x * 256 + threadIdx.x;
    int c = i & 63;
    const float M = (float)(HB * HN);
    float mean = bnsum[c] / M;
    float var  = bnss[c] / M - mean * mean;
    float inv  = rsqrtf(var + 1e-5f);
    float h = gamma[c] * (h2[i] - mean) * inv + beta[c];
    out[i] = fmaxf(h, 0.f) + x[i];
}

extern "C" void kernel_launch(void* const* d_in, const int* in_sizes, int n_in,
                              void* d_out, int out_size, void* d_ws, size_t ws_size,
                              hipStream_t stream) {
    const float* x     = (const float*)d_in[0];
    const float* W     = (const float*)d_in[1];
    const float* bias  = (const float*)d_in[2];
    const float* gamma = (const float*)d_in[3];
    const float* beta  = (const float*)d_in[4];
    float* out = (float*)d_out;
    (void)in_sizes; (void)n_in;

    char* ws = (char*)d_ws;
    size_t off = 0;
    float*        xsq     = (float*)(ws + off);        off += (size_t)HB * HN * 4;
    float*        h1      = (float*)(ws + off);        off += (size_t)HB * HN * HC * 4;
    float*        h2      = (float*)(ws + off);        off += (size_t)HB * HN * HC * 4;
    int*          Dv      = (int*)(ws + off);          off += (size_t)HB * HN * 4;
    int*          indeg   = (int*)(ws + off);          off += (size_t)HB * HN * 4;
    unsigned int* pairs   = (unsigned int*)(ws + off); off += (size_t)NPAIRS * 4;
    float*        bnsum   = (float*)(ws + off);        off += 256;
    float*        bnss    = (float*)(ws + off);        off += 256;
    int*          paircnt = (int*)(ws + off);          off += 256;
    float*        xT      = (float*)(ws + off);        // z aliases xT (dead after kNN)
    float*        z       = (float*)(ws + off);
    off += (size_t)HB * HE * HC * 4;   // max(xT, z) = z
    size_t base_need = off;
    unsigned int* kcache  = (unsigned int*)(ws + off);
    size_t cache_need = off + (size_t)HB * HN * NSLOT * 64 * 4;   // +84.9 MB

    if (ws_size < base_need) {
        hg11_sentinel<<<(out_size + 255) / 256, 256, 0, stream>>>(out, out_size);
        return;
    }
    const int use_cache = (ws_size >= cache_need) ? 1 : 0;

    const int EDGE_WAVES = NPAIRS + HB * HE2;    // 103312, divisible by 4

    hg11_init<<<(HB * HN + 255) / 256, 256, 0, stream>>>(Dv, indeg, paircnt, bnsum, bnss);
    hg11_linear<<<HB * HN, 64, 0, stream>>>(x, W, bias, h1, xsq, xT);
    hg11_knn_count<<<HB * (HN / HRPB), 256, 0, stream>>>(xT, xsq, Dv, kcache, use_cache);
    if (use_cache)
        hg11_knn_sel_cached<<<HB * (HN / HRPB), 256, 0, stream>>>(kcache, Dv, indeg, pairs, paircnt);
    else
        hg11_knn_sel_full<<<HB * (HN / HRPB), 256, 0, stream>>>(xT, xsq, Dv, indeg, pairs, paircnt);
    hg11_scale<<<(HB * HN * HC) / 256, 256, 0, stream>>>(h1, indeg);
    hg11_zero<<<(HB * HN * HC) / 256, 256, 0, stream>>>(z, h2);
    hg11_edge<<<EDGE_WAVES / 4, 256, 0, stream>>>(pairs, Dv, h1, z);
    hg11_gscatter<<<(NPAIRS * 64) / 256, 256, 0, stream>>>(pairs, z, h2);
    hg11_gfinish<<<(HB * HN) / 4, 256, 0, stream>>>(z, indeg, h2);
    hg11_bnstats<<<256, 256, 0, stream>>>(h2, bnsum, bnss);
    hg11_final<<<(HB * HN * HC) / 256, 256, 0, stream>>>(h2, x, gamma, beta, bnsum, bnss, out);
}

// Round 12
// 516.190 us; speedup vs baseline: 1.6222x; 1.1648x over previous
//
#include <hip/hip_runtime.h>

// HGNN layer, v12 — fp32. v11 kcache split; pop machinery rebuilt:
// u32-key butterfly (v_min_u32, 6 stages) + ballot winner, emission from the
// winner lane, pair bases via Dv-scan (no same-address atomics), 2-chain
// top-4 build + bitonic merge. B=4, N=2304, C=64.

#define HB    4
#define HN    2304
#define HC    64
#define HK    11             // K_NEIGS + 1
#define HL    48
#define HW    22             // windows per dim
#define HE2   484            // 22*22 local edges
#define HE    (HN + HE2)
#define HRPB  4              // rows per block == waves per block
#define NSLOT 36             // keys per lane (2304/64)
#define NPAIRS (HB * HK * HN)   // sum of Dv == 11*N per batch, exact

__global__ void hg12_sentinel(float* out, int n) {
    int i = blockIdx.x * 256 + threadIdx.x;
    if (i < n) out[i] = 12345.0f;
}

__global__ void hg12_init(int* Dv, int* indeg, float* bnsum, float* bnss) {
    int i = blockIdx.x * 256 + threadIdx.x;
    if (i < HB * HN) { Dv[i] = 0; indeg[i] = 0; }
    if (i < HC) { bnsum[i] = 0.f; bnss[i] = 0.f; }
}

// -------- linear h1 = x W^T + b, xsq, f32 transpose -----------------------
__global__ __launch_bounds__(64) void hg12_linear(const float* x, const float* W,
                                                  const float* bias, float* h1,
                                                  float* xsq, float* xT) {
    int row = blockIdx.x;            // 0..B*N-1
    int t = threadIdx.x;
    __shared__ float xr[HC];
    float v = x[row * HC + t];
    xr[t] = v;
    __syncthreads();
    float sq = v * v;
    #pragma unroll
    for (int o = 32; o > 0; o >>= 1) sq += __shfl_xor(sq, o);
    if (t == 0) xsq[row] = sq;
    int b = row / HN, n = row % HN;
    xT[(b * HC + t) * HN + n] = v;
    float acc = bias[t];
    #pragma unroll 8
    for (int c = 0; c < HC; c++) acc += xr[c] * W[t * HC + c];
    h1[row * HC + t] = acc;
}

__device__ __forceinline__ unsigned hg12_wave_min_u32(unsigned v) {
    #pragma unroll
    for (int o = 32; o > 0; o >>= 1) {
        unsigned ov = __shfl_xor(v, o);
        v = ov < v ? ov : v;
    }
    return v;
}

// sorted-insert x into ascending (q0..q3), dropping the largest
#define HG12_INS4(q0, q1, q2, q3, x)                                     \
    {                                                                    \
        unsigned long long x_ = (x), n_;                                 \
        n_ = q0 < x_ ? q0 : x_; x_ = q0 < x_ ? x_ : q0; q0 = n_;         \
        n_ = q1 < x_ ? q1 : x_; x_ = q1 < x_ ? x_ : q1; q1 = n_;         \
        n_ = q2 < x_ ? q2 : x_; x_ = q2 < x_ ? x_ : q2; q2 = n_;         \
        if (x_ < q3) q3 = x_;                                            \
    }

#define HG12_CE(u, v)                                                    \
    { unsigned long long t_ = u < v ? u : v; v = u < v ? v : u; u = t_; }

// build per-lane sorted top-4 (c0..c3) from key[NSLOT]: 2 chains + merge
#define HG12_BUILD()                                                               \
    {                                                                              \
        unsigned long long a0 = CINF, a1 = CINF, a2 = CINF, a3 = CINF;             \
        unsigned long long b0 = CINF, b1 = CINF, b2 = CINF, b3 = CINF;             \
        _Pragma("unroll")                                                          \
        for (int s = 0; s < NSLOT / 2; s++) {                                      \
            unsigned long long pa = ((unsigned long long)key[s] << 12) |           \
                                    (unsigned)((s << 6) | lane);                   \
            unsigned long long pb = ((unsigned long long)key[s + 18] << 12) |      \
                                    (unsigned)(((s + 18) << 6) | lane);            \
            HG12_INS4(a0, a1, a2, a3, pa);                                         \
            HG12_INS4(b0, b1, b2, b3, pb);                                         \
        }                                                                          \
        c0 = a0 < b3 ? a0 : b3; c1 = a1 < b2 ? a1 : b2;                            \
        c2 = a2 < b1 ? a2 : b1; c3 = a3 < b0 ? a3 : b0;                            \
        HG12_CE(c0, c2); HG12_CE(c1, c3); HG12_CE(c0, c1); HG12_CE(c2, c3);        \
    }

// pop loop: kk smallest packed keys, emission from the winner lane.
// EMIT sees: bi (member node), j (pop index). Runs with winner-lane exec.
#define HG12_EXTRACT(kk, EMIT)                                                     \
    {                                                                              \
        for (int j = 0; j < (kk); j++) {                                           \
            unsigned hk = (unsigned)(c0 >> 12);                                    \
            unsigned mk = hg12_wave_min_u32(hk);                                   \
            unsigned long long bal = __ballot(hk == mk);                           \
            bool iswin;                                                            \
            if (__popcll(bal) == 1) {                                              \
                iswin = (hk == mk);                                                \
            } else {            /* rare exact fp tie: min m among tied lanes */    \
                unsigned mc = (hk == mk) ? (unsigned)(c0 & 0xFFFu) : 0xFFFFFFFFu;  \
                unsigned mm = hg12_wave_min_u32(mc);                               \
                iswin = (mc == mm);                                                \
            }                                                                      \
            if (iswin) {                                                           \
                int bi = (int)(c0 & 0xFFFu);                                       \
                EMIT;                                                              \
                unsigned long long popped = c0;                                    \
                c0 = c1; c1 = c2; c2 = c3; c3 = CINF;                              \
                if (c0 == CINF) {                                                  \
                    _Pragma("unroll")                                              \
                    for (int s = 0; s < NSLOT; s++) {                              \
                        unsigned long long pk =                                    \
                            ((unsigned long long)key[s] << 12) |                   \
                            (unsigned)((s << 6) | lane);                           \
                        if (pk > popped) HG12_INS4(c0, c1, c2, c3, pk);            \
                    }                                                              \
                }                                                                  \
            }                                                                      \
        }                                                                          \
    }

// -------- kNN count: untiled distance phase + key store + top-11 ----------
__global__ __launch_bounds__(256) void hg12_knn_count(const float* xT, const float* xsq,
                                                      int* Dv, unsigned int* kcache,
                                                      int storekeys) {
    __shared__ float d[HRPB][HN];      // 36 KB
    __shared__ float xr[HRPB][HC];
    const int t = threadIdx.x;
    const int b = blockIdx.x / (HN / HRPB);
    const int n0 = (blockIdx.x % (HN / HRPB)) * HRPB;
    const int r = t >> 6;
    const int lane = t & 63;
    xr[r][lane] = xT[(b * HC + lane) * HN + n0 + r];
    __syncthreads();
    float xs[HRPB];
    #pragma unroll
    for (int q = 0; q < HRPB; q++) xs[q] = xsq[b * HN + n0 + q];
    for (int m = t; m < HN; m += 256) {          // 9 iterations
        float dot0 = 0.f, dot1 = 0.f, dot2 = 0.f, dot3 = 0.f;
        #pragma unroll 8
        for (int c = 0; c < HC; c++) {
            float xv = xT[(b * HC + c) * HN + m];
            dot0 += xr[0][c] * xv;
            dot1 += xr[1][c] * xv;
            dot2 += xr[2][c] * xv;
            dot3 += xr[3][c] * xv;
        }
        float xsm = xsq[b * HN + m];
        d[0][m] = xs[0] + xsm - 2.f * dot0;
        d[1][m] = xs[1] + xsm - 2.f * dot1;
        d[2][m] = xs[2] + xsm - 2.f * dot2;
        d[3][m] = xs[3] + xsm - 2.f * dot3;
    }
    __syncthreads();

    const int p = n0 + r;
    const unsigned long long CINF = ~0ull;
    unsigned int key[NSLOT];
    unsigned long long c0, c1, c2, c3;
    const int rowbase = (b * HN + p) * NSLOT;
    #pragma unroll
    for (int s = 0; s < NSLOT; s++) {
        float f = d[r][(s << 6) | lane];
        unsigned int ub = __float_as_uint(f);
        unsigned int k = ub ^ (((unsigned int)(((int)ub) >> 31)) | 0x80000000u);
        key[s] = k;
        if (storekeys) kcache[(rowbase + s) * 64 + lane] = k;
    }
    HG12_BUILD();
    HG12_EXTRACT(HK, atomicAdd(&Dv[b * HN + bi], 1));
}

// -------- exclusive scan of Dv (9216 = 256*36) into offs ------------------
__global__ __launch_bounds__(256) void hg12_scan(const int* Dv, int* offs) {
    __shared__ int part[256];
    int t = threadIdx.x;
    int base = t * 36;
    int s = 0;
    for (int i = 0; i < 36; i++) s += max(Dv[base + i], 1);
    part[t] = s;
    __syncthreads();
    if (t == 0) { int acc = 0; for (int i = 0; i < 256; i++) { int v = part[i]; part[i] = acc; acc += v; } }
    __syncthreads();
    int acc = part[t];
    for (int i = 0; i < 36; i++) { offs[base + i] = acc; acc += max(Dv[base + i], 1); }
}

// -------- kNN select, cached keys: no distance phase, no LDS --------------
__global__ __launch_bounds__(256) void hg12_knn_sel_cached(const unsigned int* kcache,
                                                           const int* Dv, const int* offs,
                                                           int* indeg, unsigned int* pairs) {
    const int t = threadIdx.x;
    const int lane = t & 63;
    const int gw = blockIdx.x * HRPB + (t >> 6);   // global row 0..B*N-1
    const int b = gw / HN, p = gw % HN;
    const unsigned long long CINF = ~0ull;
    unsigned int key[NSLOT];
    unsigned long long c0, c1, c2, c3;
    const int rowbase = gw * NSLOT;
    #pragma unroll
    for (int s = 0; s < NSLOT; s++) key[s] = kcache[(rowbase + s) * 64 + lane];
    HG12_BUILD();
    const int kk = max(Dv[gw], 1);
    const int base = offs[gw];
    HG12_EXTRACT(kk,
        { atomicAdd(&indeg[b * HN + bi], 1);
          pairs[base + j] = ((unsigned)b << 24) | ((unsigned)p << 12) | (unsigned)bi; });
}

// -------- kNN select, full recompute (fallback when ws too small) ---------
__global__ __launch_bounds__(256) void hg12_knn_sel_full(const float* xT, const float* xsq,
                                                         const int* Dv, const int* offs,
                                                         int* indeg, unsigned int* pairs) {
    __shared__ float d[HRPB][HN];
    __shared__ float xr[HRPB][HC];
    const int t = threadIdx.x;
    const int b = blockIdx.x / (HN / HRPB);
    const int n0 = (blockIdx.x % (HN / HRPB)) * HRPB;
    const int r = t >> 6;
    const int lane = t & 63;
    xr[r][lane] = xT[(b * HC + lane) * HN + n0 + r];
    __syncthreads();
    float xs[HRPB];
    #pragma unroll
    for (int q = 0; q < HRPB; q++) xs[q] = xsq[b * HN + n0 + q];
    for (int m = t; m < HN; m += 256) {
        float dot0 = 0.f, dot1 = 0.f, dot2 = 0.f, dot3 = 0.f;
        #pragma unroll 8
        for (int c = 0; c < HC; c++) {
            float xv = xT[(b * HC + c) * HN + m];
            dot0 += xr[0][c] * xv;
            dot1 += xr[1][c] * xv;
            dot2 += xr[2][c] * xv;
            dot3 += xr[3][c] * xv;
        }
        float xsm = xsq[b * HN + m];
        d[0][m] = xs[0] + xsm - 2.f * dot0;
        d[1][m] = xs[1] + xsm - 2.f * dot1;
        d[2][m] = xs[2] + xsm - 2.f * dot2;
        d[3][m] = xs[3] + xsm - 2.f * dot3;
    }
    __syncthreads();
    const int p = n0 + r;
    const unsigned long long CINF = ~0ull;
    unsigned int key[NSLOT];
    unsigned long long c0, c1, c2, c3;
    #pragma unroll
    for (int s = 0; s < NSLOT; s++) {
        float f = d[r][(s << 6) | lane];
        unsigned int ub = __float_as_uint(f);
        key[s] = ub ^ (((unsigned int)(((int)ub) >> 31)) | 0x80000000u);
    }
    HG12_BUILD();
    const int kk = max(Dv[b * HN + p], 1);
    const int base = offs[b * HN + p];
    HG12_EXTRACT(kk,
        { atomicAdd(&indeg[b * HN + bi], 1);
          pairs[base + j] = ((unsigned)b << 24) | ((unsigned)p << 12) | (unsigned)bi; });
}

__device__ __forceinline__ int hg12_lo(int rc) { return max(0, (rc - 3) / 2); }
__device__ __forceinline__ int hg12_hi(int rc) { return min(HW - 1, rc / 2); }

// -------- y = Dv^-1/2 * h1 (in place) -------------------------------------
__global__ __launch_bounds__(256) void hg12_scale(float* h1, const int* indeg) {
    int i = blockIdx.x * 256 + threadIdx.x;
    int node = i >> 6;
    int n = node % HN;
    int r = n / HL, c = n % HL;
    int cover = max(0, hg12_hi(r) - hg12_lo(r) + 1) * max(0, hg12_hi(c) - hg12_lo(c) + 1);
    int dvn = max(indeg[node] + cover, 1);
    h1[i] *= rsqrtf((float)dvn);
}

// -------- zero z (kNN-edge part) and h2 -----------------------------------
__global__ void hg12_zero(float* z, float* h2) {
    int i = blockIdx.x * 256 + threadIdx.x;      // over B*N*C
    int b = i / (HN * HC), rem = i % (HN * HC);
    z[b * HE * HC + rem] = 0.f;
    h2[i] = 0.f;
}

// -------- fused edge kernel: kNN scatter + window means -------------------
__global__ __launch_bounds__(256) void hg12_edge(const unsigned int* pairs, const int* Dv,
                                                 const float* y, float* z) {
    int wv = (blockIdx.x * 256 + threadIdx.x) >> 6;
    int lane = threadIdx.x & 63;
    if (wv < NPAIRS) {
        unsigned int pk = pairs[wv];
        int b = pk >> 24;
        if (b >= HB) return;                     // defensive (poison)
        int p = (pk >> 12) & 0xFFF, m = pk & 0xFFF;
        float invde = 1.f / (float)max(Dv[b * HN + p], 1);
        atomicAdd(&z[(b * HE + p) * HC + lane], y[(b * HN + m) * HC + lane] * invde);
    } else {
        int w2 = wv - NPAIRS;
        if (w2 >= HB * HE2) return;
        int b = w2 / HE2, w = w2 % HE2;
        int wr = w / HW, wc = w % HW;
        float acc = 0.f;
        #pragma unroll
        for (int i = 0; i < 5; i++)
            #pragma unroll
            for (int j = 0; j < 5; j++)
                acc += y[(b * HN + (wr * 2 + i) * HL + wc * 2 + j) * HC + lane];
        z[(b * HE + HN + w) * HC + lane] = acc * (1.f / 25.f);
    }
}

// -------- h2[m] += z[p] over the pair list (atomic) -----------------------
__global__ __launch_bounds__(256) void hg12_gscatter(const unsigned int* pairs,
                                                     const float* z, float* h2) {
    int idx = (blockIdx.x * 256 + threadIdx.x) >> 6;
    int lane = threadIdx.x & 63;
    if (idx >= NPAIRS) return;
    unsigned int pk = pairs[idx];
    int b = pk >> 24;
    if (b >= HB) return;                         // defensive (poison)
    int p = (pk >> 12) & 0xFFF, m = pk & 0xFFF;
    atomicAdd(&h2[(b * HN + m) * HC + lane], z[(b * HE + p) * HC + lane]);
}

// -------- add window contributions + final Dv^-1/2 scale ------------------
__global__ __launch_bounds__(256) void hg12_gfinish(const float* z, const int* indeg, float* h2) {
    int wave = (blockIdx.x * 256 + threadIdx.x) >> 6;  // one wave per (b, node)
    int lane = threadIdx.x & 63;
    int b = wave / HN, n = wave % HN;
    int g = b * HN + n;
    float acc = h2[g * HC + lane];
    int r = n / HL, c = n % HL;
    int rlo = hg12_lo(r), rhi = hg12_hi(r), clo = hg12_lo(c), chi = hg12_hi(c);
    for (int wr = rlo; wr <= rhi; wr++)
        for (int wc = clo; wc <= chi; wc++)
            acc += z[(b * HE + HN + wr * HW + wc) * HC + lane];
    int dvn = max(indeg[g] + max(0, rhi - rlo + 1) * max(0, chi - clo + 1), 1);
    h2[g * HC + lane] = acc * rsqrtf((float)dvn);
}

// -------- BN stats --------------------------------------------------------
__global__ __launch_bounds__(256) void hg12_bnstats(const float* h2, float* bnsum, float* bnss) {
    int t = threadIdx.x;
    int c = t & 63, rg = t >> 6;
    int row0 = blockIdx.x * 36;      // 256 blocks * 36 rows = 9216
    float s = 0.f, ss = 0.f;
    for (int r = rg; r < 36; r += 4) {
        float v = h2[(row0 + r) * HC + c];
        s += v; ss += v * v;
    }
    __shared__ float ls[256], lss[256];
    ls[t] = s; lss[t] = ss;
    __syncthreads();
    if (t < 64) {
        s  = ls[t]  + ls[t + 64]  + ls[t + 128]  + ls[t + 192];
        ss = lss[t] + lss[t + 64] + lss[t + 128] + lss[t + 192];
        atomicAdd(&bnsum[t], s);
        atomicAdd(&bnss[t], ss);
    }
}

// -------- BN + ReLU + residual --------------------------------------------
__global__ __launch_bounds__(256) void hg12_final(const float* h2, const float* x,
                                                  const float* gamma, const float* beta,
                                                  const float* bnsum, const float* bnss,
                                                  float* out) {
    int i = blockIdx.x * 256 + threadIdx.x;
    int c = i & 63;
    const float M = (float)(HB * HN);
    float mean = bnsum[c] / M;
    float var  = bnss[c] / M - mean * mean;
    float inv  = rsqrtf(var + 1e-5f);
    float h = gamma[c] * (h2[i] - mean) * inv + beta[c];
    out[i] = fmaxf(h, 0.f) + x[i];
}

extern "C" void kernel_launch(void* const* d_in, const int* in_sizes, int n_in,
                              void* d_out, int out_size, void* d_ws, size_t ws_size,
                              hipStream_t stream) {
    const float* x     = (const float*)d_in[0];
    const float* W     = (const float*)d_in[1];
    const float* bias  = (const float*)d_in[2];
    const float* gamma = (const float*)d_in[3];
    const float* beta  = (const float*)d_in[4];
    float* out = (float*)d_out;
    (void)in_sizes; (void)n_in;

    char* ws = (char*)d_ws;
    size_t off = 0;
    float*        xsq     = (float*)(ws + off);        off += (size_t)HB * HN * 4;
    float*        h1      = (float*)(ws + off);        off += (size_t)HB * HN * HC * 4;
    float*        h2      = (float*)(ws + off);        off += (size_t)HB * HN * HC * 4;
    int*          Dv      = (int*)(ws + off);          off += (size_t)HB * HN * 4;
    int*          indeg   = (int*)(ws + off);          off += (size_t)HB * HN * 4;
    int*          offs    = (int*)(ws + off);          off += (size_t)HB * HN * 4;
    unsigned int* pairs   = (unsigned int*)(ws + off); off += (size_t)NPAIRS * 4;
    float*        bnsum   = (float*)(ws + off);        off += 256;
    float*        bnss    = (float*)(ws + off);        off += 256;
    float*        xT      = (float*)(ws + off);        // z aliases xT (dead after kNN)
    float*        z       = (float*)(ws + off);
    off += (size_t)HB * HE * HC * 4;   // max(xT, z) = z
    size_t base_need = off;
    unsigned int* kcache  = (unsigned int*)(ws + off);
    size_t cache_need = off + (size_t)HB * HN * NSLOT * 64 * 4;   // +84.9 MB

    if (ws_size < base_need) {
        hg12_sentinel<<<(out_size + 255) / 256, 256, 0, stream>>>(out, out_size);
        return;
    }
    const int use_cache = (ws_size >= cache_need) ? 1 : 0;

    const int EDGE_WAVES = NPAIRS + HB * HE2;    // 103312, divisible by 4

    hg12_init<<<(HB * HN + 255) / 256, 256, 0, stream>>>(Dv, indeg, bnsum, bnss);
    hg12_linear<<<HB * HN, 64, 0, stream>>>(x, W, bias, h1, xsq, xT);
    hg12_knn_count<<<HB * (HN / HRPB), 256, 0, stream>>>(xT, xsq, Dv, kcache, use_cache);
    hg12_scan<<<1, 256, 0, stream>>>(Dv, offs);
    if (use_cache)
        hg12_knn_sel_cached<<<HB * (HN / HRPB), 256, 0, stream>>>(kcache, Dv, offs, indeg, pairs);
    else
        hg12_knn_sel_full<<<HB * (HN / HRPB), 256, 0, stream>>>(xT, xsq, Dv, offs, indeg, pairs);
    hg12_scale<<<(HB * HN * HC) / 256, 256, 0, stream>>>(h1, indeg);
    hg12_zero<<<(HB * HN * HC) / 256, 256, 0, stream>>>(z, h2);
    hg12_edge<<<EDGE_WAVES / 4, 256, 0, stream>>>(pairs, Dv, h1, z);
    hg12_gscatter<<<(NPAIRS * 64) / 256, 256, 0, stream>>>(pairs, z, h2);
    hg12_gfinish<<<(HB * HN) / 4, 256, 0, stream>>>(z, indeg, h2);
    hg12_bnstats<<<256, 256, 0, stream>>>(h2, bnsum, bnss);
    hg12_final<<<(HB * HN * HC) / 256, 256, 0, stream>>>(h2, x, gamma, beta, bnsum, bnss, out);
}

// Round 13
// 418.201 us; speedup vs baseline: 2.0023x; 1.2343x over previous
//
#include <hip/hip_runtime.h>

// HGNN layer, v13 — fp32. kNN selection via threshold (binary radix search
// for the kk-th smallest key) + fully parallel emission. Kills the v12 tail
// (OccupancyPercent 4.7%): no more O(kk) serial pop loops. B=4, N=2304, C=64.

#define HB    4
#define HN    2304
#define HC    64
#define HK    11             // K_NEIGS + 1
#define HL    48
#define HW    22             // windows per dim
#define HE2   484            // 22*22 local edges
#define HE    (HN + HE2)
#define HRPB  4              // rows per block == waves per block
#define NSLOT 36             // keys per lane (2304/64)
#define NPAIRS (HB * HK * HN)   // sum of Dv == 11*N per batch, exact

__global__ void hg13_sentinel(float* out, int n) {
    int i = blockIdx.x * 256 + threadIdx.x;
    if (i < n) out[i] = 12345.0f;
}

__global__ void hg13_init(int* Dv, int* indeg, float* bnsum, float* bnss) {
    int i = blockIdx.x * 256 + threadIdx.x;
    if (i < HB * HN) { Dv[i] = 0; indeg[i] = 0; }
    if (i < HC) { bnsum[i] = 0.f; bnss[i] = 0.f; }
}

// -------- linear h1 = x W^T + b, xsq, f32 transpose -----------------------
__global__ __launch_bounds__(64) void hg13_linear(const float* x, const float* W,
                                                  const float* bias, float* h1,
                                                  float* xsq, float* xT) {
    int row = blockIdx.x;            // 0..B*N-1
    int t = threadIdx.x;
    __shared__ float xr[HC];
    float v = x[row * HC + t];
    xr[t] = v;
    __syncthreads();
    float sq = v * v;
    #pragma unroll
    for (int o = 32; o > 0; o >>= 1) sq += __shfl_xor(sq, o);
    if (t == 0) xsq[row] = sq;
    int b = row / HN, n = row % HN;
    xT[(b * HC + t) * HN + n] = v;
    float acc = bias[t];
    #pragma unroll 8
    for (int c = 0; c < HC; c++) acc += xr[c] * W[t * HC + c];
    h1[row * HC + t] = acc;
}

// -------- kk-th smallest key of a row (wave-cooperative bisection) --------
// Lane's slot s holds node m = (s<<6)|lane. Returns T (the kk-th smallest
// u32 key), cntLess (# keys < T, wave total), take (# to take among ==T).
__device__ __forceinline__ void hg13_kth(const unsigned (&key)[NSLOT], int kk,
                                         unsigned& T, int& cntLess, int& take) {
    unsigned andv = 0xFFFFFFFFu, orv = 0u;
    #pragma unroll
    for (int s = 0; s < NSLOT; s++) { andv &= key[s]; orv |= key[s]; }
    #pragma unroll
    for (int o = 32; o > 0; o >>= 1) {
        andv &= (unsigned)__shfl_xor((int)andv, o);
        orv  |= (unsigned)__shfl_xor((int)orv, o);
    }
    unsigned diff = andv ^ orv;
    if (diff == 0u) { T = andv; cntLess = 0; take = kk; return; }
    int tstart = 31 - __builtin_clz(diff);
    unsigned lowmask = (tstart == 31) ? 0xFFFFFFFFu : ((1u << (tstart + 1)) - 1u);
    unsigned pref = andv & ~lowmask;     // common high bits, rest 0
    int r = kk;
    for (int t = tstart; t >= 0; t--) {  // wave-uniform trip count
        unsigned pt = pref >> t;         // prefix with bit t = 0
        int c = 0;
        #pragma unroll
        for (int s = 0; s < NSLOT; s++) c += ((key[s] >> t) == pt) ? 1 : 0;
        #pragma unroll
        for (int o = 32; o > 0; o >>= 1) c += __shfl_xor(c, o);
        if (r > c) { r -= c; pref |= (1u << t); }
    }
    T = pref; cntLess = kk - r; take = r;
}

// exclusive scan of v over 64 lanes; returns (excl, total)
__device__ __forceinline__ void hg13_scan64(int v, int lane, int& excl, int& total) {
    int inc = v;
    #pragma unroll
    for (int o = 1; o < 64; o <<= 1) {
        int u = __shfl_up(inc, o);
        if (lane >= o) inc += u;
    }
    excl = inc - v;
    total = __shfl(inc, 63);
}

// -------- kNN count: untiled distance phase + key store + top-11 ----------
__global__ __launch_bounds__(256) void hg13_knn_count(const float* xT, const float* xsq,
                                                      int* Dv, unsigned int* kcache,
                                                      int storekeys) {
    __shared__ float d[HRPB][HN];      // 36 KB
    __shared__ float xr[HRPB][HC];
    const int t = threadIdx.x;
    const int b = blockIdx.x / (HN / HRPB);
    const int n0 = (blockIdx.x % (HN / HRPB)) * HRPB;
    const int r = t >> 6;
    const int lane = t & 63;
    xr[r][lane] = xT[(b * HC + lane) * HN + n0 + r];
    __syncthreads();
    float xs[HRPB];
    #pragma unroll
    for (int q = 0; q < HRPB; q++) xs[q] = xsq[b * HN + n0 + q];
    for (int m = t; m < HN; m += 256) {          // 9 iterations
        float dot0 = 0.f, dot1 = 0.f, dot2 = 0.f, dot3 = 0.f;
        #pragma unroll 8
        for (int c = 0; c < HC; c++) {
            float xv = xT[(b * HC + c) * HN + m];
            dot0 += xr[0][c] * xv;
            dot1 += xr[1][c] * xv;
            dot2 += xr[2][c] * xv;
            dot3 += xr[3][c] * xv;
        }
        float xsm = xsq[b * HN + m];
        d[0][m] = xs[0] + xsm - 2.f * dot0;
        d[1][m] = xs[1] + xsm - 2.f * dot1;
        d[2][m] = xs[2] + xsm - 2.f * dot2;
        d[3][m] = xs[3] + xsm - 2.f * dot3;
    }
    __syncthreads();

    const int p = n0 + r;
    unsigned int key[NSLOT];
    const int rowbase = (b * HN + p) * NSLOT;
    #pragma unroll
    for (int s = 0; s < NSLOT; s++) {
        float f = d[r][(s << 6) | lane];
        unsigned int ub = __float_as_uint(f);
        unsigned int k = ub ^ (((unsigned int)(((int)ub) >> 31)) | 0x80000000u);
        key[s] = k;
        if (storekeys) kcache[(rowbase + s) * 64 + lane] = k;
    }
    unsigned T; int cntLess, take;
    hg13_kth(key, HK, T, cntLess, take);
    #pragma unroll
    for (int s = 0; s < NSLOT; s++)
        if (key[s] < T) atomicAdd(&Dv[b * HN + ((s << 6) | lane)], 1);
    int lastm = -1;
    for (int t2 = 0; t2 < take; t2++) {
        int mc = 0x7FFFFFFF;
        #pragma unroll
        for (int s = 0; s < NSLOT; s++) {
            int m = (s << 6) | lane;
            if (key[s] == T && m > lastm && m < mc) mc = m;
        }
        int mmin = mc;
        #pragma unroll
        for (int o = 32; o > 0; o >>= 1) {
            int ov = __shfl_xor(mmin, o);
            mmin = ov < mmin ? ov : mmin;
        }
        if (mc == mmin) atomicAdd(&Dv[b * HN + mmin], 1);   // unique owner lane
        lastm = mmin;
    }
}

// -------- exclusive scan of Dv (9216 = 256*36) into offs ------------------
__global__ __launch_bounds__(256) void hg13_scan(const int* Dv, int* offs) {
    __shared__ int part[256];
    int t = threadIdx.x;
    int base = t * 36;
    int s = 0;
    for (int i = 0; i < 36; i++) s += max(Dv[base + i], 1);
    part[t] = s;
    __syncthreads();
    if (t == 0) { int acc = 0; for (int i = 0; i < 256; i++) { int v = part[i]; part[i] = acc; acc += v; } }
    __syncthreads();
    int acc = part[t];
    for (int i = 0; i < 36; i++) { offs[base + i] = acc; acc += max(Dv[base + i], 1); }
}

// -------- shared select body: threshold + parallel emission ---------------
__device__ __forceinline__ void hg13_select_emit(const unsigned (&key)[NSLOT],
                                                 int b, int p, int lane, int kk, int base,
                                                 int* indeg, unsigned int* pairs) {
    unsigned T; int cntLess, take;
    hg13_kth(key, kk, T, cntLess, take);
    int cl = 0;
    #pragma unroll
    for (int s = 0; s < NSLOT; s++) cl += (key[s] < T) ? 1 : 0;
    int off, tot;
    hg13_scan64(cl, lane, off, tot);
    int w = 0;
    #pragma unroll
    for (int s = 0; s < NSLOT; s++) {
        if (key[s] < T) {
            int m = (s << 6) | lane;
            atomicAdd(&indeg[b * HN + m], 1);
            pairs[base + off + w] =
                ((unsigned)b << 24) | ((unsigned)p << 12) | (unsigned)m;
            w++;
        }
    }
    int lastm = -1;
    for (int t2 = 0; t2 < take; t2++) {
        int mc = 0x7FFFFFFF;
        #pragma unroll
        for (int s = 0; s < NSLOT; s++) {
            int m = (s << 6) | lane;
            if (key[s] == T && m > lastm && m < mc) mc = m;
        }
        int mmin = mc;
        #pragma unroll
        for (int o = 32; o > 0; o >>= 1) {
            int ov = __shfl_xor(mmin, o);
            mmin = ov < mmin ? ov : mmin;
        }
        if (mc == mmin) {                           // unique owner lane
            atomicAdd(&indeg[b * HN + mmin], 1);
            pairs[base + cntLess + t2] =
                ((unsigned)b << 24) | ((unsigned)p << 12) | (unsigned)mmin;
        }
        lastm = mmin;
    }
}

// -------- kNN select, cached keys: no distance phase, no LDS --------------
__global__ __launch_bounds__(256) void hg13_knn_sel_cached(const unsigned int* kcache,
                                                           const int* Dv, const int* offs,
                                                           int* indeg, unsigned int* pairs) {
    const int t = threadIdx.x;
    const int lane = t & 63;
    const int gw = blockIdx.x * HRPB + (t >> 6);   // global row 0..B*N-1
    const int b = gw / HN, p = gw % HN;
    unsigned int key[NSLOT];
    const int rowbase = gw * NSLOT;
    #pragma unroll
    for (int s = 0; s < NSLOT; s++) key[s] = kcache[(rowbase + s) * 64 + lane];
    hg13_select_emit(key, b, p, lane, max(Dv[gw], 1), offs[gw], indeg, pairs);
}

// -------- kNN select, full recompute (fallback when ws too small) ---------
__global__ __launch_bounds__(256) void hg13_knn_sel_full(const float* xT, const float* xsq,
                                                         const int* Dv, const int* offs,
                                                         int* indeg, unsigned int* pairs) {
    __shared__ float d[HRPB][HN];
    __shared__ float xr[HRPB][HC];
    const int t = threadIdx.x;
    const int b = blockIdx.x / (HN / HRPB);
    const int n0 = (blockIdx.x % (HN / HRPB)) * HRPB;
    const int r = t >> 6;
    const int lane = t & 63;
    xr[r][lane] = xT[(b * HC + lane) * HN + n0 + r];
    __syncthreads();
    float xs[HRPB];
    #pragma unroll
    for (int q = 0; q < HRPB; q++) xs[q] = xsq[b * HN + n0 + q];
    for (int m = t; m < HN; m += 256) {
        float dot0 = 0.f, dot1 = 0.f, dot2 = 0.f, dot3 = 0.f;
        #pragma unroll 8
        for (int c = 0; c < HC; c++) {
            float xv = xT[(b * HC + c) * HN + m];
            dot0 += xr[0][c] * xv;
            dot1 += xr[1][c] * xv;
            dot2 += xr[2][c] * xv;
            dot3 += xr[3][c] * xv;
        }
        float xsm = xsq[b * HN + m];
        d[0][m] = xs[0] + xsm - 2.f * dot0;
        d[1][m] = xs[1] + xsm - 2.f * dot1;
        d[2][m] = xs[2] + xsm - 2.f * dot2;
        d[3][m] = xs[3] + xsm - 2.f * dot3;
    }
    __syncthreads();
    const int p = n0 + r;
    unsigned int key[NSLOT];
    #pragma unroll
    for (int s = 0; s < NSLOT; s++) {
        float f = d[r][(s << 6) | lane];
        unsigned int ub = __float_as_uint(f);
        key[s] = ub ^ (((unsigned int)(((int)ub) >> 31)) | 0x80000000u);
    }
    const int gw = b * HN + p;
    hg13_select_emit(key, b, p, lane, max(Dv[gw], 1), offs[gw], indeg, pairs);
}

__device__ __forceinline__ int hg13_lo(int rc) { return max(0, (rc - 3) / 2); }
__device__ __forceinline__ int hg13_hi(int rc) { return min(HW - 1, rc / 2); }

// -------- y = Dv^-1/2 * h1 (in place) -------------------------------------
__global__ __launch_bounds__(256) void hg13_scale(float* h1, const int* indeg) {
    int i = blockIdx.x * 256 + threadIdx.x;
    int node = i >> 6;
    int n = node % HN;
    int r = n / HL, c = n % HL;
    int cover = max(0, hg13_hi(r) - hg13_lo(r) + 1) * max(0, hg13_hi(c) - hg13_lo(c) + 1);
    int dvn = max(indeg[node] + cover, 1);
    h1[i] *= rsqrtf((float)dvn);
}

// -------- zero z (kNN-edge part) and h2 -----------------------------------
__global__ void hg13_zero(float* z, float* h2) {
    int i = blockIdx.x * 256 + threadIdx.x;      // over B*N*C
    int b = i / (HN * HC), rem = i % (HN * HC);
    z[b * HE * HC + rem] = 0.f;
    h2[i] = 0.f;
}

// -------- fused edge kernel: kNN scatter + window means -------------------
__global__ __launch_bounds__(256) void hg13_edge(const unsigned int* pairs, const int* Dv,
                                                 const float* y, float* z) {
    int wv = (blockIdx.x * 256 + threadIdx.x) >> 6;
    int lane = threadIdx.x & 63;
    if (wv < NPAIRS) {
        unsigned int pk = pairs[wv];
        int b = pk >> 24;
        if (b >= HB) return;                     // defensive (poison)
        int p = (pk >> 12) & 0xFFF, m = pk & 0xFFF;
        float invde = 1.f / (float)max(Dv[b * HN + p], 1);
        atomicAdd(&z[(b * HE + p) * HC + lane], y[(b * HN + m) * HC + lane] * invde);
    } else {
        int w2 = wv - NPAIRS;
        if (w2 >= HB * HE2) return;
        int b = w2 / HE2, w = w2 % HE2;
        int wr = w / HW, wc = w % HW;
        float acc = 0.f;
        #pragma unroll
        for (int i = 0; i < 5; i++)
            #pragma unroll
            for (int j = 0; j < 5; j++)
                acc += y[(b * HN + (wr * 2 + i) * HL + wc * 2 + j) * HC + lane];
        z[(b * HE + HN + w) * HC + lane] = acc * (1.f / 25.f);
    }
}

// -------- h2[m] += z[p] over the pair list (atomic) -----------------------
__global__ __launch_bounds__(256) void hg13_gscatter(const unsigned int* pairs,
                                                     const float* z, float* h2) {
    int idx = (blockIdx.x * 256 + threadIdx.x) >> 6;
    int lane = threadIdx.x & 63;
    if (idx >= NPAIRS) return;
    unsigned int pk = pairs[idx];
    int b = pk >> 24;
    if (b >= HB) return;                         // defensive (poison)
    int p = (pk >> 12) & 0xFFF, m = pk & 0xFFF;
    atomicAdd(&h2[(b * HN + m) * HC + lane], z[(b * HE + p) * HC + lane]);
}

// -------- add window contributions + final Dv^-1/2 scale ------------------
__global__ __launch_bounds__(256) void hg13_gfinish(const float* z, const int* indeg, float* h2) {
    int wave = (blockIdx.x * 256 + threadIdx.x) >> 6;  // one wave per (b, node)
    int lane = threadIdx.x & 63;
    int b = wave / HN, n = wave % HN;
    int g = b * HN + n;
    float acc = h2[g * HC + lane];
    int r = n / HL, c = n % HL;
    int rlo = hg13_lo(r), rhi = hg13_hi(r), clo = hg13_lo(c), chi = hg13_hi(c);
    for (int wr = rlo; wr <= rhi; wr++)
        for (int wc = clo; wc <= chi; wc++)
            acc += z[(b * HE + HN + wr * HW + wc) * HC + lane];
    int dvn = max(indeg[g] + max(0, rhi - rlo + 1) * max(0, chi - clo + 1), 1);
    h2[g * HC + lane] = acc * rsqrtf((float)dvn);
}

// -------- BN stats --------------------------------------------------------
__global__ __launch_bounds__(256) void hg13_bnstats(const float* h2, float* bnsum, float* bnss) {
    int t = threadIdx.x;
    int c = t & 63, rg = t >> 6;
    int row0 = blockIdx.x * 36;      // 256 blocks * 36 rows = 9216
    float s = 0.f, ss = 0.f;
    for (int r = rg; r < 36; r += 4) {
        float v = h2[(row0 + r) * HC + c];
        s += v; ss += v * v;
    }
    __shared__ float ls[256], lss[256];
    ls[t] = s; lss[t] = ss;
    __syncthreads();
    if (t < 64) {
        s  = ls[t]  + ls[t + 64]  + ls[t + 128]  + ls[t + 192];
        ss = lss[t] + lss[t + 64] + lss[t + 128] + lss[t + 192];
        atomicAdd(&bnsum[t], s);
        atomicAdd(&bnss[t], ss);
    }
}

// -------- BN + ReLU + residual --------------------------------------------
__global__ __launch_bounds__(256) void hg13_final(const float* h2, const float* x,
                                                  const float* gamma, const float* beta,
                                                  const float* bnsum, const float* bnss,
                                                  float* out) {
    int i = blockIdx.x * 256 + threadIdx.x;
    int c = i & 63;
    const float M = (float)(HB * HN);
    float mean = bnsum[c] / M;
    float var  = bnss[c] / M - mean * mean;
    float inv  = rsqrtf(var + 1e-5f);
    float h = gamma[c] * (h2[i] - mean) * inv + beta[c];
    out[i] = fmaxf(h, 0.f) + x[i];
}

extern "C" void kernel_launch(void* const* d_in, const int* in_sizes, int n_in,
                              void* d_out, int out_size, void* d_ws, size_t ws_size,
                              hipStream_t stream) {
    const float* x     = (const float*)d_in[0];
    const float* W     = (const float*)d_in[1];
    const float* bias  = (const float*)d_in[2];
    const float* gamma = (const float*)d_in[3];
    const float* beta  = (const float*)d_in[4];
    float* out = (float*)d_out;
    (void)in_sizes; (void)n_in;

    char* ws = (char*)d_ws;
    size_t off = 0;
    float*        xsq     = (float*)(ws + off);        off += (size_t)HB * HN * 4;
    float*        h1      = (float*)(ws + off);        off += (size_t)HB * HN * HC * 4;
    float*        h2      = (float*)(ws + off);        off += (size_t)HB * HN * HC * 4;
    int*          Dv      = (int*)(ws + off);          off += (size_t)HB * HN * 4;
    int*          indeg   = (int*)(ws + off);          off += (size_t)HB * HN * 4;
    int*          offs    = (int*)(ws + off);          off += (size_t)HB * HN * 4;
    unsigned int* pairs   = (unsigned int*)(ws + off); off += (size_t)NPAIRS * 4;
    float*        bnsum   = (float*)(ws + off);        off += 256;
    float*        bnss    = (float*)(ws + off);        off += 256;
    float*        xT      = (float*)(ws + off);        // z aliases xT (dead after kNN)
    float*        z       = (float*)(ws + off);
    off += (size_t)HB * HE * HC * 4;   // max(xT, z) = z
    size_t base_need = off;
    unsigned int* kcache  = (unsigned int*)(ws + off);
    size_t cache_need = off + (size_t)HB * HN * NSLOT * 64 * 4;   // +84.9 MB

    if (ws_size < base_need) {
        hg13_sentinel<<<(out_size + 255) / 256, 256, 0, stream>>>(out, out_size);
        return;
    }
    const int use_cache = (ws_size >= cache_need) ? 1 : 0;

    const int EDGE_WAVES = NPAIRS + HB * HE2;    // 103312, divisible by 4

    hg13_init<<<(HB * HN + 255) / 256, 256, 0, stream>>>(Dv, indeg, bnsum, bnss);
    hg13_linear<<<HB * HN, 64, 0, stream>>>(x, W, bias, h1, xsq, xT);
    hg13_knn_count<<<HB * (HN / HRPB), 256, 0, stream>>>(xT, xsq, Dv, kcache, use_cache);
    hg13_scan<<<1, 256, 0, stream>>>(Dv, offs);
    if (use_cache)
        hg13_knn_sel_cached<<<HB * (HN / HRPB), 256, 0, stream>>>(kcache, Dv, offs, indeg, pairs);
    else
        hg13_knn_sel_full<<<HB * (HN / HRPB), 256, 0, stream>>>(xT, xsq, Dv, offs, indeg, pairs);
    hg13_scale<<<(HB * HN * HC) / 256, 256, 0, stream>>>(h1, indeg);
    hg13_zero<<<(HB * HN * HC) / 256, 256, 0, stream>>>(z, h2);
    hg13_edge<<<EDGE_WAVES / 4, 256, 0, stream>>>(pairs, Dv, h1, z);
    hg13_gscatter<<<(NPAIRS * 64) / 256, 256, 0, stream>>>(pairs, z, h2);
    hg13_gfinish<<<(HB * HN) / 4, 256, 0, stream>>>(z, indeg, h2);
    hg13_bnstats<<<256, 256, 0, stream>>>(h2, bnsum, bnss);
    hg13_final<<<(HB * HN * HC) / 256, 256, 0, stream>>>(h2, x, gamma, beta, bnsum, bnss, out);
}

// Round 14
// 375.218 us; speedup vs baseline: 2.2317x; 1.1146x over previous
//
#include <hip/hip_runtime.h>

// HGNN layer, v14 — fp32. v13 pipeline; count kernel rebuilt: distance loop
// with ds_read_b128 row-vectors + float2 m-vectorization (bit-identical fp),
// and fixed-k(11) selection via the v12 pop machinery (bisection kept only in
// select where kk varies). B=4, N=2304, C=64.

#define HB    4
#define HN    2304
#define HC    64
#define HK    11             // K_NEIGS + 1
#define HL    48
#define HW    22             // windows per dim
#define HE2   484            // 22*22 local edges
#define HE    (HN + HE2)
#define HRPB  4              // rows per block == waves per block
#define NSLOT 36             // keys per lane (2304/64)
#define NPAIRS (HB * HK * HN)   // sum of Dv == 11*N per batch, exact

__global__ void hg14_sentinel(float* out, int n) {
    int i = blockIdx.x * 256 + threadIdx.x;
    if (i < n) out[i] = 12345.0f;
}

__global__ void hg14_init(int* Dv, int* indeg, float* bnsum, float* bnss) {
    int i = blockIdx.x * 256 + threadIdx.x;
    if (i < HB * HN) { Dv[i] = 0; indeg[i] = 0; }
    if (i < HC) { bnsum[i] = 0.f; bnss[i] = 0.f; }
}

// -------- linear h1 = x W^T + b, xsq, f32 transpose -----------------------
__global__ __launch_bounds__(64) void hg14_linear(const float* x, const float* W,
                                                  const float* bias, float* h1,
                                                  float* xsq, float* xT) {
    int row = blockIdx.x;            // 0..B*N-1
    int t = threadIdx.x;
    __shared__ float xr[HC];
    float v = x[row * HC + t];
    xr[t] = v;
    __syncthreads();
    float sq = v * v;
    #pragma unroll
    for (int o = 32; o > 0; o >>= 1) sq += __shfl_xor(sq, o);
    if (t == 0) xsq[row] = sq;
    int b = row / HN, n = row % HN;
    xT[(b * HC + t) * HN + n] = v;
    float acc = bias[t];
    #pragma unroll 8
    for (int c = 0; c < HC; c++) acc += xr[c] * W[t * HC + c];
    h1[row * HC + t] = acc;
}

// ======== pop machinery (v12-proven): for fixed kk=11 in count ============
__device__ __forceinline__ unsigned hg14_wave_min_u32(unsigned v) {
    #pragma unroll
    for (int o = 32; o > 0; o >>= 1) {
        unsigned ov = __shfl_xor(v, o);
        v = ov < v ? ov : v;
    }
    return v;
}

#define HG14_INS4(q0, q1, q2, q3, x)                                     \
    {                                                                    \
        unsigned long long x_ = (x), n_;                                 \
        n_ = q0 < x_ ? q0 : x_; x_ = q0 < x_ ? x_ : q0; q0 = n_;         \
        n_ = q1 < x_ ? q1 : x_; x_ = q1 < x_ ? x_ : q1; q1 = n_;         \
        n_ = q2 < x_ ? q2 : x_; x_ = q2 < x_ ? x_ : q2; q2 = n_;         \
        if (x_ < q3) q3 = x_;                                            \
    }

#define HG14_CE(u, v)                                                    \
    { unsigned long long t_ = u < v ? u : v; v = u < v ? v : u; u = t_; }

#define HG14_BUILD()                                                               \
    {                                                                              \
        unsigned long long a0 = CINF, a1 = CINF, a2 = CINF, a3 = CINF;             \
        unsigned long long b0 = CINF, b1 = CINF, b2 = CINF, b3 = CINF;             \
        _Pragma("unroll")                                                          \
        for (int s = 0; s < NSLOT / 2; s++) {                                      \
            unsigned long long pa = ((unsigned long long)key[s] << 12) |           \
                                    (unsigned)((s << 6) | lane);                   \
            unsigned long long pb = ((unsigned long long)key[s + 18] << 12) |      \
                                    (unsigned)(((s + 18) << 6) | lane);            \
            HG14_INS4(a0, a1, a2, a3, pa);                                         \
            HG14_INS4(b0, b1, b2, b3, pb);                                         \
        }                                                                          \
        c0 = a0 < b3 ? a0 : b3; c1 = a1 < b2 ? a1 : b2;                            \
        c2 = a2 < b1 ? a2 : b1; c3 = a3 < b0 ? a3 : b0;                            \
        HG14_CE(c0, c2); HG14_CE(c1, c3); HG14_CE(c0, c1); HG14_CE(c2, c3);        \
    }

#define HG14_EXTRACT(kk, EMIT)                                                     \
    {                                                                              \
        for (int j = 0; j < (kk); j++) {                                           \
            unsigned hk = (unsigned)(c0 >> 12);                                    \
            unsigned mk = hg14_wave_min_u32(hk);                                   \
            unsigned long long bal = __ballot(hk == mk);                           \
            bool iswin;                                                            \
            if (__popcll(bal) == 1) {                                              \
                iswin = (hk == mk);                                                \
            } else {                                                               \
                unsigned mc = (hk == mk) ? (unsigned)(c0 & 0xFFFu) : 0xFFFFFFFFu;  \
                unsigned mm = hg14_wave_min_u32(mc);                               \
                iswin = (mc == mm);                                                \
            }                                                                      \
            if (iswin) {                                                           \
                int bi = (int)(c0 & 0xFFFu);                                       \
                EMIT;                                                              \
                unsigned long long popped = c0;                                    \
                c0 = c1; c1 = c2; c2 = c3; c3 = CINF;                              \
                if (c0 == CINF) {                                                  \
                    _Pragma("unroll")                                              \
                    for (int s = 0; s < NSLOT; s++) {                              \
                        unsigned long long pk =                                    \
                            ((unsigned long long)key[s] << 12) |                   \
                            (unsigned)((s << 6) | lane);                           \
                        if (pk > popped) HG14_INS4(c0, c1, c2, c3, pk);            \
                    }                                                              \
                }                                                                  \
            }                                                                      \
        }                                                                          \
    }

// ======== bisection machinery (v13-proven): for variable kk in select =====
__device__ __forceinline__ void hg14_kth(const unsigned (&key)[NSLOT], int kk,
                                         unsigned& T, int& cntLess, int& take) {
    unsigned andv = 0xFFFFFFFFu, orv = 0u;
    #pragma unroll
    for (int s = 0; s < NSLOT; s++) { andv &= key[s]; orv |= key[s]; }
    #pragma unroll
    for (int o = 32; o > 0; o >>= 1) {
        andv &= (unsigned)__shfl_xor((int)andv, o);
        orv  |= (unsigned)__shfl_xor((int)orv, o);
    }
    unsigned diff = andv ^ orv;
    if (diff == 0u) { T = andv; cntLess = 0; take = kk; return; }
    int tstart = 31 - __builtin_clz(diff);
    unsigned lowmask = (tstart == 31) ? 0xFFFFFFFFu : ((1u << (tstart + 1)) - 1u);
    unsigned pref = andv & ~lowmask;
    int r = kk;
    for (int t = tstart; t >= 0; t--) {
        unsigned pt = pref >> t;
        int c = 0;
        #pragma unroll
        for (int s = 0; s < NSLOT; s++) c += ((key[s] >> t) == pt) ? 1 : 0;
        #pragma unroll
        for (int o = 32; o > 0; o >>= 1) c += __shfl_xor(c, o);
        if (r > c) { r -= c; pref |= (1u << t); }
    }
    T = pref; cntLess = kk - r; take = r;
}

__device__ __forceinline__ void hg14_scan64(int v, int lane, int& excl, int& total) {
    int inc = v;
    #pragma unroll
    for (int o = 1; o < 64; o <<= 1) {
        int u = __shfl_up(inc, o);
        if (lane >= o) inc += u;
    }
    excl = inc - v;
    total = __shfl(inc, 63);
}

// -------- kNN count: vectorized distance + key store + pop top-11 ---------
__global__ __launch_bounds__(256) void hg14_knn_count(const float* xT, const float* xsq,
                                                      int* Dv, unsigned int* kcache,
                                                      int storekeys) {
    __shared__ float d[HRPB][HN];                // 36 KB
    __shared__ __align__(16) float xrt[HC][HRPB];// [c][row] -> b128 uniform reads
    const int t = threadIdx.x;
    const int b = blockIdx.x / (HN / HRPB);
    const int n0 = (blockIdx.x % (HN / HRPB)) * HRPB;
    const int r = t >> 6;
    const int lane = t & 63;
    xrt[lane][r] = xT[(b * HC + lane) * HN + n0 + r];
    __syncthreads();
    float xs[HRPB];
    #pragma unroll
    for (int q = 0; q < HRPB; q++) xs[q] = xsq[b * HN + n0 + q];

    // per-m accumulation stays c-ascending scalar fp: bit-identical to v13
    #pragma unroll
    for (int i = 0; i < 4; i++) {                // m = 0..2047, float2 per thread
        const int m = 512 * i + 2 * t;
        float2 d0 = {0.f, 0.f}, d1 = {0.f, 0.f}, d2 = {0.f, 0.f}, d3 = {0.f, 0.f};
        #pragma unroll 8
        for (int c = 0; c < HC; c++) {
            float4 xq = *reinterpret_cast<const float4*>(&xrt[c][0]);
            float2 xv = *reinterpret_cast<const float2*>(&xT[(b * HC + c) * HN + m]);
            d0.x += xq.x * xv.x; d0.y += xq.x * xv.y;
            d1.x += xq.y * xv.x; d1.y += xq.y * xv.y;
            d2.x += xq.z * xv.x; d2.y += xq.z * xv.y;
            d3.x += xq.w * xv.x; d3.y += xq.w * xv.y;
        }
        float s0 = xsq[b * HN + m], s1 = xsq[b * HN + m + 1];
        *reinterpret_cast<float2*>(&d[0][m]) =
            make_float2(xs[0] + s0 - 2.f * d0.x, xs[0] + s1 - 2.f * d0.y);
        *reinterpret_cast<float2*>(&d[1][m]) =
            make_float2(xs[1] + s0 - 2.f * d1.x, xs[1] + s1 - 2.f * d1.y);
        *reinterpret_cast<float2*>(&d[2][m]) =
            make_float2(xs[2] + s0 - 2.f * d2.x, xs[2] + s1 - 2.f * d2.y);
        *reinterpret_cast<float2*>(&d[3][m]) =
            make_float2(xs[3] + s0 - 2.f * d3.x, xs[3] + s1 - 2.f * d3.y);
    }
    {                                            // scalar tail m = 2048 + t
        const int m = 2048 + t;
        float d0 = 0.f, d1 = 0.f, d2 = 0.f, d3 = 0.f;
        #pragma unroll 8
        for (int c = 0; c < HC; c++) {
            float4 xq = *reinterpret_cast<const float4*>(&xrt[c][0]);
            float xv = xT[(b * HC + c) * HN + m];
            d0 += xq.x * xv; d1 += xq.y * xv; d2 += xq.z * xv; d3 += xq.w * xv;
        }
        float sm = xsq[b * HN + m];
        d[0][m] = xs[0] + sm - 2.f * d0;
        d[1][m] = xs[1] + sm - 2.f * d1;
        d[2][m] = xs[2] + sm - 2.f * d2;
        d[3][m] = xs[3] + sm - 2.f * d3;
    }
    __syncthreads();

    const int p = n0 + r;
    const unsigned long long CINF = ~0ull;
    unsigned int key[NSLOT];
    unsigned long long c0, c1, c2, c3;
    const int rowbase = (b * HN + p) * NSLOT;
    #pragma unroll
    for (int s = 0; s < NSLOT; s++) {
        float f = d[r][(s << 6) | lane];
        unsigned int ub = __float_as_uint(f);
        unsigned int k = ub ^ (((unsigned int)(((int)ub) >> 31)) | 0x80000000u);
        key[s] = k;
        if (storekeys) kcache[(rowbase + s) * 64 + lane] = k;
    }
    HG14_BUILD();
    HG14_EXTRACT(HK, atomicAdd(&Dv[b * HN + bi], 1));
}

// -------- exclusive scan of Dv (9216 = 256*36) into offs ------------------
__global__ __launch_bounds__(256) void hg14_scan(const int* Dv, int* offs) {
    __shared__ int part[256];
    int t = threadIdx.x;
    int base = t * 36;
    int s = 0;
    for (int i = 0; i < 36; i++) s += max(Dv[base + i], 1);
    part[t] = s;
    __syncthreads();
    if (t == 0) { int acc = 0; for (int i = 0; i < 256; i++) { int v = part[i]; part[i] = acc; acc += v; } }
    __syncthreads();
    int acc = part[t];
    for (int i = 0; i < 36; i++) { offs[base + i] = acc; acc += max(Dv[base + i], 1); }
}

// -------- select body: threshold + parallel emission (v13-proven) ---------
__device__ __forceinline__ void hg14_select_emit(const unsigned (&key)[NSLOT],
                                                 int b, int p, int lane, int kk, int base,
                                                 int* indeg, unsigned int* pairs) {
    unsigned T; int cntLess, take;
    hg14_kth(key, kk, T, cntLess, take);
    int cl = 0;
    #pragma unroll
    for (int s = 0; s < NSLOT; s++) cl += (key[s] < T) ? 1 : 0;
    int off, tot;
    hg14_scan64(cl, lane, off, tot);
    int w = 0;
    #pragma unroll
    for (int s = 0; s < NSLOT; s++) {
        if (key[s] < T) {
            int m = (s << 6) | lane;
            atomicAdd(&indeg[b * HN + m], 1);
            pairs[base + off + w] =
                ((unsigned)b << 24) | ((unsigned)p << 12) | (unsigned)m;
            w++;
        }
    }
    int lastm = -1;
    for (int t2 = 0; t2 < take; t2++) {
        int mc = 0x7FFFFFFF;
        #pragma unroll
        for (int s = 0; s < NSLOT; s++) {
            int m = (s << 6) | lane;
            if (key[s] == T && m > lastm && m < mc) mc = m;
        }
        int mmin = mc;
        #pragma unroll
        for (int o = 32; o > 0; o >>= 1) {
            int ov = __shfl_xor(mmin, o);
            mmin = ov < mmin ? ov : mmin;
        }
        if (mc == mmin) {
            atomicAdd(&indeg[b * HN + mmin], 1);
            pairs[base + cntLess + t2] =
                ((unsigned)b << 24) | ((unsigned)p << 12) | (unsigned)mmin;
        }
        lastm = mmin;
    }
}

// -------- kNN select, cached keys -----------------------------------------
__global__ __launch_bounds__(256) void hg14_knn_sel_cached(const unsigned int* kcache,
                                                           const int* Dv, const int* offs,
                                                           int* indeg, unsigned int* pairs) {
    const int t = threadIdx.x;
    const int lane = t & 63;
    const int gw = blockIdx.x * HRPB + (t >> 6);   // global row 0..B*N-1
    const int b = gw / HN, p = gw % HN;
    unsigned int key[NSLOT];
    const int rowbase = gw * NSLOT;
    #pragma unroll
    for (int s = 0; s < NSLOT; s++) key[s] = kcache[(rowbase + s) * 64 + lane];
    hg14_select_emit(key, b, p, lane, max(Dv[gw], 1), offs[gw], indeg, pairs);
}

// -------- kNN select, full recompute (fallback) ---------------------------
__global__ __launch_bounds__(256) void hg14_knn_sel_full(const float* xT, const float* xsq,
                                                         const int* Dv, const int* offs,
                                                         int* indeg, unsigned int* pairs) {
    __shared__ float d[HRPB][HN];
    __shared__ float xr[HRPB][HC];
    const int t = threadIdx.x;
    const int b = blockIdx.x / (HN / HRPB);
    const int n0 = (blockIdx.x % (HN / HRPB)) * HRPB;
    const int r = t >> 6;
    const int lane = t & 63;
    xr[r][lane] = xT[(b * HC + lane) * HN + n0 + r];
    __syncthreads();
    float xs[HRPB];
    #pragma unroll
    for (int q = 0; q < HRPB; q++) xs[q] = xsq[b * HN + n0 + q];
    for (int m = t; m < HN; m += 256) {
        float dot0 = 0.f, dot1 = 0.f, dot2 = 0.f, dot3 = 0.f;
        #pragma unroll 8
        for (int c = 0; c < HC; c++) {
            float xv = xT[(b * HC + c) * HN + m];
            dot0 += xr[0][c] * xv;
            dot1 += xr[1][c] * xv;
            dot2 += xr[2][c] * xv;
            dot3 += xr[3][c] * xv;
        }
        float xsm = xsq[b * HN + m];
        d[0][m] = xs[0] + xsm - 2.f * dot0;
        d[1][m] = xs[1] + xsm - 2.f * dot1;
        d[2][m] = xs[2] + xsm - 2.f * dot2;
        d[3][m] = xs[3] + xsm - 2.f * dot3;
    }
    __syncthreads();
    const int p = n0 + r;
    unsigned int key[NSLOT];
    #pragma unroll
    for (int s = 0; s < NSLOT; s++) {
        float f = d[r][(s << 6) | lane];
        unsigned int ub = __float_as_uint(f);
        key[s] = ub ^ (((unsigned int)(((int)ub) >> 31)) | 0x80000000u);
    }
    const int gw = b * HN + p;
    hg14_select_emit(key, b, p, lane, max(Dv[gw], 1), offs[gw], indeg, pairs);
}

__device__ __forceinline__ int hg14_lo(int rc) { return max(0, (rc - 3) / 2); }
__device__ __forceinline__ int hg14_hi(int rc) { return min(HW - 1, rc / 2); }

// -------- y = Dv^-1/2 * h1 (in place) -------------------------------------
__global__ __launch_bounds__(256) void hg14_scale(float* h1, const int* indeg) {
    int i = blockIdx.x * 256 + threadIdx.x;
    int node = i >> 6;
    int n = node % HN;
    int r = n / HL, c = n % HL;
    int cover = max(0, hg14_hi(r) - hg14_lo(r) + 1) * max(0, hg14_hi(c) - hg14_lo(c) + 1);
    int dvn = max(indeg[node] + cover, 1);
    h1[i] *= rsqrtf((float)dvn);
}

// -------- zero z (kNN-edge part) and h2 -----------------------------------
__global__ void hg14_zero(float* z, float* h2) {
    int i = blockIdx.x * 256 + threadIdx.x;      // over B*N*C
    int b = i / (HN * HC), rem = i % (HN * HC);
    z[b * HE * HC + rem] = 0.f;
    h2[i] = 0.f;
}

// -------- fused edge kernel: kNN scatter + window means -------------------
__global__ __launch_bounds__(256) void hg14_edge(const unsigned int* pairs, const int* Dv,
                                                 const float* y, float* z) {
    int wv = (blockIdx.x * 256 + threadIdx.x) >> 6;
    int lane = threadIdx.x & 63;
    if (wv < NPAIRS) {
        unsigned int pk = pairs[wv];
        int b = pk >> 24;
        if (b >= HB) return;                     // defensive (poison)
        int p = (pk >> 12) & 0xFFF, m = pk & 0xFFF;
        float invde = 1.f / (float)max(Dv[b * HN + p], 1);
        atomicAdd(&z[(b * HE + p) * HC + lane], y[(b * HN + m) * HC + lane] * invde);
    } else {
        int w2 = wv - NPAIRS;
        if (w2 >= HB * HE2) return;
        int b = w2 / HE2, w = w2 % HE2;
        int wr = w / HW, wc = w % HW;
        float acc = 0.f;
        #pragma unroll
        for (int i = 0; i < 5; i++)
            #pragma unroll
            for (int j = 0; j < 5; j++)
                acc += y[(b * HN + (wr * 2 + i) * HL + wc * 2 + j) * HC + lane];
        z[(b * HE + HN + w) * HC + lane] = acc * (1.f / 25.f);
    }
}

// -------- h2[m] += z[p] over the pair list (atomic) -----------------------
__global__ __launch_bounds__(256) void hg14_gscatter(const unsigned int* pairs,
                                                     const float* z, float* h2) {
    int idx = (blockIdx.x * 256 + threadIdx.x) >> 6;
    int lane = threadIdx.x & 63;
    if (idx >= NPAIRS) return;
    unsigned int pk = pairs[idx];
    int b = pk >> 24;
    if (b >= HB) return;                         // defensive (poison)
    int p = (pk >> 12) & 0xFFF, m = pk & 0xFFF;
    atomicAdd(&h2[(b * HN + m) * HC + lane], z[(b * HE + p) * HC + lane]);
}

// -------- add window contributions + final Dv^-1/2 scale ------------------
__global__ __launch_bounds__(256) void hg14_gfinish(const float* z, const int* indeg, float* h2) {
    int wave = (blockIdx.x * 256 + threadIdx.x) >> 6;  // one wave per (b, node)
    int lane = threadIdx.x & 63;
    int b = wave / HN, n = wave % HN;
    int g = b * HN + n;
    float acc = h2[g * HC + lane];
    int r = n / HL, c = n % HL;
    int rlo = hg14_lo(r), rhi = hg14_hi(r), clo = hg14_lo(c), chi = hg14_hi(c);
    for (int wr = rlo; wr <= rhi; wr++)
        for (int wc = clo; wc <= chi; wc++)
            acc += z[(b * HE + HN + wr * HW + wc) * HC + lane];
    int dvn = max(indeg[g] + max(0, rhi - rlo + 1) * max(0, chi - clo + 1), 1);
    h2[g * HC + lane] = acc * rsqrtf((float)dvn);
}

// -------- BN stats --------------------------------------------------------
__global__ __launch_bounds__(256) void hg14_bnstats(const float* h2, float* bnsum, float* bnss) {
    int t = threadIdx.x;
    int c = t & 63, rg = t >> 6;
    int row0 = blockIdx.x * 36;      // 256 blocks * 36 rows = 9216
    float s = 0.f, ss = 0.f;
    for (int r = rg; r < 36; r += 4) {
        float v = h2[(row0 + r) * HC + c];
        s += v; ss += v * v;
    }
    __shared__ float ls[256], lss[256];
    ls[t] = s; lss[t] = ss;
    __syncthreads();
    if (t < 64) {
        s  = ls[t]  + ls[t + 64]  + ls[t + 128]  + ls[t + 192];
        ss = lss[t] + lss[t + 64] + lss[t + 128] + lss[t + 192];
        atomicAdd(&bnsum[t], s);
        atomicAdd(&bnss[t], ss);
    }
}

// -------- BN + ReLU + residual --------------------------------------------
__global__ __launch_bounds__(256) void hg14_final(const float* h2, const float* x,
                                                  const float* gamma, const float* beta,
                                                  const float* bnsum, const float* bnss,
                                                  float* out) {
    int i = blockIdx.x * 256 + threadIdx.x;
    int c = i & 63;
    const float M = (float)(HB * HN);
    float mean = bnsum[c] / M;
    float var  = bnss[c] / M - mean * mean;
    float inv  = rsqrtf(var + 1e-5f);
    float h = gamma[c] * (h2[i] - mean) * inv + beta[c];
    out[i] = fmaxf(h, 0.f) + x[i];
}

extern "C" void kernel_launch(void* const* d_in, const int* in_sizes, int n_in,
                              void* d_out, int out_size, void* d_ws, size_t ws_size,
                              hipStream_t stream) {
    const float* x     = (const float*)d_in[0];
    const float* W     = (const float*)d_in[1];
    const float* bias  = (const float*)d_in[2];
    const float* gamma = (const float*)d_in[3];
    const float* beta  = (const float*)d_in[4];
    float* out = (float*)d_out;
    (void)in_sizes; (void)n_in;

    char* ws = (char*)d_ws;
    size_t off = 0;
    float*        xsq     = (float*)(ws + off);        off += (size_t)HB * HN * 4;
    float*        h1      = (float*)(ws + off);        off += (size_t)HB * HN * HC * 4;
    float*        h2      = (float*)(ws + off);        off += (size_t)HB * HN * HC * 4;
    int*          Dv      = (int*)(ws + off);          off += (size_t)HB * HN * 4;
    int*          indeg   = (int*)(ws + off);          off += (size_t)HB * HN * 4;
    int*          offs    = (int*)(ws + off);          off += (size_t)HB * HN * 4;
    unsigned int* pairs   = (unsigned int*)(ws + off); off += (size_t)NPAIRS * 4;
    float*        bnsum   = (float*)(ws + off);        off += 256;
    float*        bnss    = (float*)(ws + off);        off += 256;
    float*        xT      = (float*)(ws + off);        // z aliases xT (dead after kNN)
    float*        z       = (float*)(ws + off);
    off += (size_t)HB * HE * HC * 4;   // max(xT, z) = z
    size_t base_need = off;
    unsigned int* kcache  = (unsigned int*)(ws + off);
    size_t cache_need = off + (size_t)HB * HN * NSLOT * 64 * 4;   // +84.9 MB

    if (ws_size < base_need) {
        hg14_sentinel<<<(out_size + 255) / 256, 256, 0, stream>>>(out, out_size);
        return;
    }
    const int use_cache = (ws_size >= cache_need) ? 1 : 0;

    const int EDGE_WAVES = NPAIRS + HB * HE2;    // 103312, divisible by 4

    hg14_init<<<(HB * HN + 255) / 256, 256, 0, stream>>>(Dv, indeg, bnsum, bnss);
    hg14_linear<<<HB * HN, 64, 0, stream>>>(x, W, bias, h1, xsq, xT);
    hg14_knn_count<<<HB * (HN / HRPB), 256, 0, stream>>>(xT, xsq, Dv, kcache, use_cache);
    hg14_scan<<<1, 256, 0, stream>>>(Dv, offs);
    if (use_cache)
        hg14_knn_sel_cached<<<HB * (HN / HRPB), 256, 0, stream>>>(kcache, Dv, offs, indeg, pairs);
    else
        hg14_knn_sel_full<<<HB * (HN / HRPB), 256, 0, stream>>>(xT, xsq, Dv, offs, indeg, pairs);
    hg14_scale<<<(HB * HN * HC) / 256, 256, 0, stream>>>(h1, indeg);
    hg14_zero<<<(HB * HN * HC) / 256, 256, 0, stream>>>(z, h2);
    hg14_edge<<<EDGE_WAVES / 4, 256, 0, stream>>>(pairs, Dv, h1, z);
    hg14_gscatter<<<(NPAIRS * 64) / 256, 256, 0, stream>>>(pairs, z, h2);
    hg14_gfinish<<<(HB * HN) / 4, 256, 0, stream>>>(z, indeg, h2);
    hg14_bnstats<<<256, 256, 0, stream>>>(h2, bnsum, bnss);
    hg14_final<<<(HB * HN * HC) / 256, 256, 0, stream>>>(h2, x, gamma, beta, bnsum, bnss, out);
}